// Round 13
// baseline (224.740 us; speedup 1.0000x reference)
//
#include <hip/hip_runtime.h>

#define DINF 128
#define DHID 128
#define DOUTF 64

#define NSLICE 32       // edge slices (16 per graph); CSR node-major, slice-minor
#define NSLICE_LOG 5
#define CHUNKC 12544    // cnt histogram chunk (49 KB LDS)
#define NCHUNKC 4
#define CHUNKF 3136     // fill cursor chunk (12.5 KB LDS)
#define NCHUNKF 16

typedef unsigned short ushort_t;
typedef unsigned int uint_t;
typedef __attribute__((ext_vector_type(8))) short bf16x8;
typedef __attribute__((ext_vector_type(4))) float f32x4;

__device__ __forceinline__ ushort_t f2b(float x) {   // f32 -> bf16 RNE
    uint_t u = __float_as_uint(x);
    u += 0x7fffu + ((u >> 16) & 1u);
    return (ushort_t)(u >> 16);
}
__device__ __forceinline__ float b2f_lo(uint_t u) { return __uint_as_float(u << 16); }
__device__ __forceinline__ float b2f_hi(uint_t u) { return __uint_as_float(u & 0xffff0000u); }

// ---- per-(slice, node) histograms of src and dst; plain stores only ----
__global__ void cnt_kernel(const int* __restrict__ s1, const int* __restrict__ d1,
                           const int* __restrict__ s2, const int* __restrict__ d2,
                           int* __restrict__ cntS, int* __restrict__ cntD, int N, int ne) {
    extern __shared__ int h[];
    int t = threadIdx.x;
    for (int j = t; j < CHUNKC; j += 1024) h[j] = 0;
    __syncthreads();

    int lo = blockIdx.x * CHUNKC;
    int q = blockIdx.y;
    bool isSrc = blockIdx.z == 0;
    int SL = (2 * ne) / NSLICE;
    int g = q >= (NSLICE / 2);
    const int* p = g ? (isSrc ? s2 : d2) : (isSrc ? s1 : d1);
    int base = g ? ne : 0;
    int e0 = q * SL - base;
    int e1 = e0 + SL;
    for (int i = e0 + t; i < e1; i += 1024) {
        int v = p[i] - lo;
        if ((unsigned)v < (unsigned)CHUNKC) atomicAdd(&h[v], 1);
    }
    __syncthreads();

    int* c = (isSrc ? cntS : cntD) + (size_t)q * N;
    for (int j = t; j < CHUNKC; j += 1024) {
        int node = lo + j;
        if (node < N) c[node] = h[j];
    }
}

// ---- degrees from slice-count sums; store rsqrt(max(deg,1)) ----
__global__ void degred_kernel(const int* __restrict__ cntS, const int* __restrict__ cntD,
                              float* __restrict__ rs, int N) {
    int v = blockIdx.x * 256 + threadIdx.x;
    if (v >= N) return;
    int o1 = 0, i1 = 0, o2 = 0, i2 = 0;
    #pragma unroll
    for (int q = 0; q < NSLICE / 2; ++q) {
        o1 += cntS[(size_t)q * N + v];
        i1 += cntD[(size_t)q * N + v];
    }
    #pragma unroll
    for (int q = NSLICE / 2; q < NSLICE; ++q) {
        o2 += cntS[(size_t)q * N + v];
        i2 += cntD[(size_t)q * N + v];
    }
    rs[v]                  = rsqrtf(fmaxf((float)o1, 1.0f));   // rs1o
    rs[N + v]              = rsqrtf(fmaxf((float)i1, 1.0f));   // rs1i
    rs[2 * (size_t)N + v]  = rsqrtf(fmaxf((float)o2, 1.0f));   // rs2o
    rs[3 * (size_t)N + v]  = rsqrtf(fmaxf((float)i2, 1.0f));   // rs2i
}

// ---- scan phase 1: NODE-MAJOR; element i=(v*NSLICE+q) reads cntD[q][v] ----
__global__ void scan1_kernel(const int* __restrict__ cntD, int* __restrict__ offs,
                             int* __restrict__ bsum, int N, int m) {
    __shared__ int warp_sums[4];
    int t = threadIdx.x;
    int lane = t & 63;
    int wid = t >> 6;
    int base = blockIdx.x * 1024 + t * 4;

    int v4[4];
    int tot = 0;
    #pragma unroll
    for (int j = 0; j < 4; ++j) {
        int i = base + j;
        int d = 0;
        if (i < m) {
            int v = i >> NSLICE_LOG, q = i & (NSLICE - 1);
            d = cntD[(size_t)q * N + v];
        }
        v4[j] = d; tot += d;
    }
    int x = tot;
    #pragma unroll
    for (int off = 1; off < 64; off <<= 1) {
        int y = __shfl_up(x, off, 64);
        if (lane >= off) x += y;
    }
    if (lane == 63) warp_sums[wid] = x;
    __syncthreads();
    int wbase = 0;
    for (int w = 0; w < wid; ++w) wbase += warp_sums[w];
    int run = wbase + x - tot;
    #pragma unroll
    for (int j = 0; j < 4; ++j) {
        int i = base + j;
        if (i < m) offs[i] = run;
        run += v4[j];
    }
    if (t == 255) bsum[blockIdx.x] = run;
}

// ---- scan phase 2 ----
__global__ void scan2_kernel(int* __restrict__ bsum, int* __restrict__ offs, int nb, int m) {
    int lane = threadIdx.x;
    int run = 0;
    for (int base = 0; base < nb; base += 64) {
        int i = base + lane;
        int v = (i < nb) ? bsum[i] : 0;
        int x = v;
        #pragma unroll
        for (int off = 1; off < 64; off <<= 1) {
            int y = __shfl_up(x, off, 64);
            if (lane >= off) x += y;
        }
        if (i < nb) bsum[i] = run + x - v;
        run += __shfl(x, 63, 64);
    }
    if (lane == 0) offs[m] = run;
}

// ---- scan phase 3 ----
__global__ void scan3_kernel(int* __restrict__ offs, const int* __restrict__ bsum, int m) {
    int base = blockIdx.x * 1024 + threadIdx.x * 4;
    int add = bsum[blockIdx.x];
    #pragma unroll
    for (int j = 0; j < 4; ++j) {
        int i = base + j;
        if (i < m) offs[i] += add;
    }
}

// ---- CSR fill: LDS cursors, zero global atomics, 4B entries (src only) ----
__global__ void fill_kernel(const int* __restrict__ s1, const int* __restrict__ d1,
                            const int* __restrict__ s2, const int* __restrict__ d2,
                            const int* __restrict__ offs, int* __restrict__ csr,
                            int N, int ne) {
    extern __shared__ int cur[];
    int t = threadIdx.x;
    int lo = blockIdx.x * CHUNKF;
    int q = blockIdx.y;
    int lim = N - lo < CHUNKF ? N - lo : CHUNKF;
    for (int j = t; j < lim; j += 1024)
        cur[j] = offs[(size_t)(lo + j) * NSLICE + q];
    __syncthreads();

    int SL = (2 * ne) / NSLICE;
    int g = q >= (NSLICE / 2);
    const int* src = g ? s2 : s1;
    const int* dst = g ? d2 : d1;
    int base = g ? ne : 0;
    int e0 = q * SL - base;
    int sl4 = SL & ~4095;
    int e1 = e0 + SL;

    for (int i = e0 + t * 4; i < e0 + sl4; i += 4096) {
        int4 d4 = *(const int4*)(dst + i);
        #pragma unroll
        for (int j = 0; j < 4; ++j) {
            int dd = ((const int*)&d4)[j] - lo;
            if ((unsigned)dd < (unsigned)lim) {
                int pos = atomicAdd(&cur[dd], 1);
                csr[pos] = src[i + j];
            }
        }
    }
    for (int i = e0 + sl4 + t; i < e1; i += 1024) {
        int dd = dst[i] - lo;
        if ((unsigned)dd < (unsigned)lim) {
            int pos = atomicAdd(&cur[dd], 1);
            csr[pos] = src[i];
        }
    }
}

// ---- W convert+transpose, both weights in one launch ----
__global__ void wconv2_kernel(const float* __restrict__ W1, const float* __restrict__ W2,
                              ushort_t* __restrict__ Wt1, ushort_t* __restrict__ Wt2) {
    int tid = blockIdx.x * 256 + threadIdx.x;
    if (tid < 128 * 128) {
        int ncol = tid / 128, k = tid % 128;
        Wt1[tid] = f2b(W1[(size_t)k * 128 + ncol]);
    } else if (tid < 128 * 128 + 64 * 128) {
        int t2 = tid - 128 * 128;
        int ncol = t2 / 128, k = t2 % 128;
        Wt2[t2] = f2b(W2[(size_t)k * 64 + ncol]);
    }
}

// ---- MFMA GEMM: Y[n,NOUT](bf16) = X[n,128] @ W ----
template<int NOUT, bool F32IN>
__global__ __launch_bounds__(256) void mfma_gemm_kernel(const void* __restrict__ Xv,
                                                        const ushort_t* __restrict__ Wt,
                                                        ushort_t* __restrict__ Y, int n) {
    constexpr int CT = NOUT / 16;
    const int lane = threadIdx.x & 63;
    const int wv = threadIdx.x >> 6;
    const int row0 = blockIdx.x * 64 + wv * 16;
    const int arow = row0 + (lane & 15);
    const int arc = arow < n ? arow : (n - 1);

    f32x4 acc[CT];
    #pragma unroll
    for (int ct = 0; ct < CT; ++ct) acc[ct] = (f32x4)(0.f);

    #pragma unroll
    for (int kk = 0; kk < 4; ++kk) {
        const int k0 = kk * 32 + (lane >> 4) * 8;
        bf16x8 a;
        if (F32IN) {
            const float* xp = (const float*)Xv + (size_t)arc * 128 + k0;
            float4 u0 = *(const float4*)xp;
            float4 u1 = *(const float4*)(xp + 4);
            a[0] = (short)f2b(u0.x); a[1] = (short)f2b(u0.y);
            a[2] = (short)f2b(u0.z); a[3] = (short)f2b(u0.w);
            a[4] = (short)f2b(u1.x); a[5] = (short)f2b(u1.y);
            a[6] = (short)f2b(u1.z); a[7] = (short)f2b(u1.w);
        } else {
            a = *(const bf16x8*)((const ushort_t*)Xv + (size_t)arc * 128 + k0);
        }
        #pragma unroll
        for (int ct = 0; ct < CT; ++ct) {
            bf16x8 b = *(const bf16x8*)(Wt + (size_t)(ct * 16 + (lane & 15)) * 128 + k0);
            acc[ct] = __builtin_amdgcn_mfma_f32_16x16x32_bf16(a, b, acc[ct], 0, 0, 0);
        }
    }

    const int orow0 = row0 + (lane >> 4) * 4;
    const int col = lane & 15;
    #pragma unroll
    for (int ct = 0; ct < CT; ++ct) {
        #pragma unroll
        for (int r = 0; r < 4; ++r) {
            int row = orow0 + r;
            if (row < n) Y[(size_t)row * NOUT + ct * 16 + col] = f2b(acc[ct][r]);
        }
    }
}

// ==== agg D=128: single pipelined pass over the node's full 32-slice segment ====
// per-edge weight = (e<eb ? rs1o : rs2o)[s] * (e<eb ? f1 : f2); f_g wave-uniform.
// Software pipeline: double-buffered 8-edge batches (named bufs; rule #20).
__global__ void agg128_kernel(const ushort_t* __restrict__ V, const int* __restrict__ offs,
                              const int* __restrict__ csr, const float* __restrict__ rs,
                              const float* __restrict__ bias, const float* __restrict__ attn,
                              uint_t* __restrict__ out, int n) {
    int wid = (int)(((size_t)blockIdx.x * blockDim.x + threadIdx.x) >> 6);
    int lane = threadIdx.x & 63;
    if (wid >= n) return;
    int e0 = offs[(size_t)wid << NSLICE_LOG];
    int eb = offs[((size_t)wid << NSLICE_LOG) + 16];
    int e1 = offs[((size_t)wid << NSLICE_LOG) + NSLICE];

    const float* rs1o = rs;
    const float* rs2o = rs + 2 * (size_t)n;
    float f1 = attn[0] * rs[(size_t)n + wid];
    float f2 = attn[1] * rs[3 * (size_t)n + wid];

    float acc0 = 0.f, acc1 = 0.f;

#define LOAD128(S, W, U, EB)                                                     \
    _Pragma("unroll") for (int j = 0; j < 8; ++j) S[j] = csr[(EB) + j];          \
    _Pragma("unroll") for (int j = 0; j < 8; ++j)                                \
        U[j] = ((const uint_t*)(V + (size_t)S[j] * 128))[lane];                  \
    _Pragma("unroll") for (int j = 0; j < 8; ++j) {                              \
        bool g1 = (EB) + j < eb;                                                 \
        W[j] = (g1 ? rs1o[S[j]] : rs2o[S[j]]) * (g1 ? f1 : f2);                  \
    }
#define CONS128(W, U)                                                            \
    _Pragma("unroll") for (int j = 0; j < 8; ++j) {                              \
        acc0 += W[j] * b2f_lo(U[j]); acc1 += W[j] * b2f_hi(U[j]);                \
    }

    int n8 = (e1 - e0) >> 3;
    int e = e0 + n8 * 8;
    if (n8 > 0) {
        int svA[8]; float wA[8]; uint_t uA[8];
        int svB[8]; float wB[8]; uint_t uB[8];
        LOAD128(svA, wA, uA, e0);
        int b = 1;
        for (; b + 1 < n8; b += 2) {
            LOAD128(svB, wB, uB, e0 + b * 8);
            CONS128(wA, uA);
            LOAD128(svA, wA, uA, e0 + (b + 1) * 8);
            CONS128(wB, uB);
        }
        if (b < n8) {
            LOAD128(svB, wB, uB, e0 + b * 8);
            CONS128(wA, uA);
            CONS128(wB, uB);
        } else {
            CONS128(wA, uA);
        }
    }
    for (; e < e1; ++e) {
        int s = csr[e];
        bool g1 = e < eb;
        float w = (g1 ? rs1o[s] : rs2o[s]) * (g1 ? f1 : f2);
        uint_t u = ((const uint_t*)(V + (size_t)s * 128))[lane];
        acc0 += w * b2f_lo(u); acc1 += w * b2f_hi(u);
    }
#undef LOAD128
#undef CONS128

    float bs = attn[0] + attn[1];
    float2 bb = ((const float2*)bias)[lane];
    float o0 = acc0 + bs * bb.x;
    float o1 = acc1 + bs * bb.y;
    out[(size_t)wid * 64 + lane] = (uint_t)f2b(o0) | ((uint_t)f2b(o1) << 16);
}

// ==== agg D=64: half-wave per edge, pipelined; f32 output ====
__global__ void agg64_kernel(const ushort_t* __restrict__ V, const int* __restrict__ offs,
                             const int* __restrict__ csr, const float* __restrict__ rs,
                             const float* __restrict__ bias, const float* __restrict__ attn,
                             float* __restrict__ out, int n) {
    int wid = (int)(((size_t)blockIdx.x * blockDim.x + threadIdx.x) >> 6);
    int lane = threadIdx.x & 63;
    int half = lane >> 5;
    int hl = lane & 31;
    if (wid >= n) return;
    int e0 = offs[(size_t)wid << NSLICE_LOG];
    int eb = offs[((size_t)wid << NSLICE_LOG) + 16];
    int e1 = offs[((size_t)wid << NSLICE_LOG) + NSLICE];

    const float* rs1o = rs;
    const float* rs2o = rs + 2 * (size_t)n;
    float f1 = attn[0] * rs[(size_t)n + wid];
    float f2 = attn[1] * rs[3 * (size_t)n + wid];

    float acc0 = 0.f, acc1 = 0.f;

#define LOAD64(S, W, U, EB)                                                      \
    _Pragma("unroll") for (int j = 0; j < 4; ++j) S[j] = csr[(EB) + 2 * j + half]; \
    _Pragma("unroll") for (int j = 0; j < 4; ++j)                                \
        U[j] = ((const uint_t*)(V + (size_t)S[j] * 64))[hl];                     \
    _Pragma("unroll") for (int j = 0; j < 4; ++j) {                              \
        bool g1 = (EB) + 2 * j + half < eb;                                      \
        W[j] = (g1 ? rs1o[S[j]] : rs2o[S[j]]) * (g1 ? f1 : f2);                  \
    }
#define CONS64(W, U)                                                             \
    _Pragma("unroll") for (int j = 0; j < 4; ++j) {                              \
        acc0 += W[j] * b2f_lo(U[j]); acc1 += W[j] * b2f_hi(U[j]);                \
    }

    int n8 = (e1 - e0) >> 3;
    int e = e0 + n8 * 8;
    if (n8 > 0) {
        int svA[4]; float wA[4]; uint_t uA[4];
        int svB[4]; float wB[4]; uint_t uB[4];
        LOAD64(svA, wA, uA, e0);
        int b = 1;
        for (; b + 1 < n8; b += 2) {
            LOAD64(svB, wB, uB, e0 + b * 8);
            CONS64(wA, uA);
            LOAD64(svA, wA, uA, e0 + (b + 1) * 8);
            CONS64(wB, uB);
        }
        if (b < n8) {
            LOAD64(svB, wB, uB, e0 + b * 8);
            CONS64(wA, uA);
            CONS64(wB, uB);
        } else {
            CONS64(wA, uA);
        }
    }
    for (; e + 2 <= e1; e += 2) {
        int ee = e + half;
        int s = csr[ee];
        bool g1 = ee < eb;
        float w = (g1 ? rs1o[s] : rs2o[s]) * (g1 ? f1 : f2);
        uint_t u = ((const uint_t*)(V + (size_t)s * 64))[hl];
        acc0 += w * b2f_lo(u); acc1 += w * b2f_hi(u);
    }
    if (e < e1 && half == 0) {
        int s = csr[e];
        bool g1 = e < eb;
        float w = (g1 ? rs1o[s] : rs2o[s]) * (g1 ? f1 : f2);
        uint_t u = ((const uint_t*)(V + (size_t)s * 64))[hl];
        acc0 += w * b2f_lo(u); acc1 += w * b2f_hi(u);
    }
#undef LOAD64
#undef CONS64

    acc0 += __shfl_xor(acc0, 32, 64);
    acc1 += __shfl_xor(acc1, 32, 64);

    if (half == 0) {
        float bs = attn[0] + attn[1];
        float2 bb = ((const float2*)bias)[hl];
        float2 o = make_float2(acc0 + bs * bb.x, acc1 + bs * bb.y);
        ((float2*)(out + (size_t)wid * 64))[hl] = o;
    }
}

extern "C" void kernel_launch(void* const* d_in, const int* in_sizes, int n_in,
                              void* d_out, int out_size, void* d_ws, size_t ws_size,
                              hipStream_t stream) {
    const float* feat = (const float*)d_in[0];
    const int* src1   = (const int*)d_in[1];
    const int* dst1   = (const int*)d_in[2];
    const int* src2   = (const int*)d_in[3];
    const int* dst2   = (const int*)d_in[4];
    const float* attn = (const float*)d_in[5];
    const float* W1   = (const float*)d_in[6];
    const float* b1   = (const float*)d_in[7];
    const float* W2   = (const float*)d_in[8];
    const float* b2   = (const float*)d_in[9];
    float* out = (float*)d_out;

    const int N  = in_sizes[0] / DINF;        // 50000
    const int NE = in_sizes[1];               // 600000
    const int M  = NSLICE * N;                // offs length (1.6M), node-major
    const int NB2 = (M + 1023) / 1024;        // scan blocks

    // workspace layout:
    // Wt1 | Wt2 | A bf16[N*128] | B bf16[N*128] | C bf16[N*64] |
    // offs[M+1] | cntS[M] | cntD[M] | rs f32[4N] | bsum[NB2]
    // csr (int[2NE] = 4.8 MB) OVERLAYS cntS (6.4 MB): counts dead after scan1.
    ushort_t* Wt1 = (ushort_t*)d_ws;
    ushort_t* Wt2 = Wt1 + 128 * 128;
    ushort_t* A   = Wt2 + 64 * 128;
    ushort_t* B   = A + (size_t)N * DHID;
    ushort_t* C   = B + (size_t)N * DHID;
    int* offs   = (int*)(C + (size_t)N * DOUTF);
    int* cntS   = offs + (M + 1);
    int* cntD   = cntS + M;
    float* rs   = (float*)(cntD + M);
    int* bsum   = (int*)(rs + 4 * (size_t)N);
    int* csr    = cntS;                       // overlay

    wconv2_kernel<<<(128 * 128 + 64 * 128 + 255) / 256, 256, 0, stream>>>(W1, W2, Wt1, Wt2);

    cnt_kernel<<<dim3(NCHUNKC, NSLICE, 2), 1024, CHUNKC * sizeof(int), stream>>>(
        src1, dst1, src2, dst2, cntS, cntD, N, NE);

    degred_kernel<<<(N + 255) / 256, 256, 0, stream>>>(cntS, cntD, rs, N);

    scan1_kernel<<<NB2, 256, 0, stream>>>(cntD, offs, bsum, N, M);
    scan2_kernel<<<1, 64, 0, stream>>>(bsum, offs, NB2, M);
    scan3_kernel<<<NB2, 256, 0, stream>>>(offs, bsum, M);

    fill_kernel<<<dim3(NCHUNKF, NSLICE), 1024, CHUNKF * sizeof(int), stream>>>(
        src1, dst1, src2, dst2, offs, csr, N, NE);

    int gb = (N + 63) / 64;
    int ab = (N + 3) / 4;
    // layer 1: A = bf16(feat @ W1) ; B = bf16(agg(A))
    mfma_gemm_kernel<DHID, true><<<gb, 256, 0, stream>>>(feat, Wt1, A, N);
    agg128_kernel<<<ab, 256, 0, stream>>>(A, offs, csr, rs, b1, attn, (uint_t*)B, N);

    // layer 2: C = bf16(B @ W2) ; out = agg(C)  (f32)
    mfma_gemm_kernel<DOUTF, false><<<gb, 256, 0, stream>>>(B, Wt2, C, N);
    agg64_kernel<<<ab, 256, 0, stream>>>(C, offs, csr, rs, b2, attn, out, N);
}

// Round 14
// 202.643 us; speedup vs baseline: 1.1090x; 1.1090x over previous
//
#include <hip/hip_runtime.h>

#define DINF 128
#define DHID 128
#define DOUTF 64

#define NSLICE 32       // edge slices (16 per graph); CSR node-major, slice-minor
#define NSLICE_LOG 5
#define CHUNKC 12544    // cnt histogram chunk (49 KB LDS)
#define NCHUNKC 4
#define CHUNKF 3136     // fill cursor chunk (12.5 KB LDS)
#define NCHUNKF 16

typedef unsigned short ushort_t;
typedef unsigned int uint_t;
typedef __attribute__((ext_vector_type(8))) short bf16x8;
typedef __attribute__((ext_vector_type(4))) float f32x4;

__device__ __forceinline__ ushort_t f2b(float x) {   // f32 -> bf16 RNE
    uint_t u = __float_as_uint(x);
    u += 0x7fffu + ((u >> 16) & 1u);
    return (ushort_t)(u >> 16);
}
__device__ __forceinline__ float b2f_lo(uint_t u) { return __uint_as_float(u << 16); }
__device__ __forceinline__ float b2f_hi(uint_t u) { return __uint_as_float(u & 0xffff0000u); }

// ---- per-(slice, node) histograms of src and dst; plain stores only ----
__global__ void cnt_kernel(const int* __restrict__ s1, const int* __restrict__ d1,
                           const int* __restrict__ s2, const int* __restrict__ d2,
                           int* __restrict__ cntS, int* __restrict__ cntD, int N, int ne) {
    extern __shared__ int h[];
    int t = threadIdx.x;
    for (int j = t; j < CHUNKC; j += 1024) h[j] = 0;
    __syncthreads();

    int lo = blockIdx.x * CHUNKC;
    int q = blockIdx.y;
    bool isSrc = blockIdx.z == 0;
    int SL = (2 * ne) / NSLICE;
    int g = q >= (NSLICE / 2);
    const int* p = g ? (isSrc ? s2 : d2) : (isSrc ? s1 : d1);
    int base = g ? ne : 0;
    int e0 = q * SL - base;
    int e1 = e0 + SL;
    for (int i = e0 + t; i < e1; i += 1024) {
        int v = p[i] - lo;
        if ((unsigned)v < (unsigned)CHUNKC) atomicAdd(&h[v], 1);
    }
    __syncthreads();

    int* c = (isSrc ? cntS : cntD) + (size_t)q * N;
    for (int j = t; j < CHUNKC; j += 1024) {
        int node = lo + j;
        if (node < N) c[node] = h[j];
    }
}

// ---- degrees from slice-count sums; store rsqrt(max(deg,1)) ----
__global__ void degred_kernel(const int* __restrict__ cntS, const int* __restrict__ cntD,
                              float* __restrict__ rs, int N) {
    int v = blockIdx.x * 256 + threadIdx.x;
    if (v >= N) return;
    int o1 = 0, i1 = 0, o2 = 0, i2 = 0;
    #pragma unroll
    for (int q = 0; q < NSLICE / 2; ++q) {
        o1 += cntS[(size_t)q * N + v];
        i1 += cntD[(size_t)q * N + v];
    }
    #pragma unroll
    for (int q = NSLICE / 2; q < NSLICE; ++q) {
        o2 += cntS[(size_t)q * N + v];
        i2 += cntD[(size_t)q * N + v];
    }
    rs[v]                  = rsqrtf(fmaxf((float)o1, 1.0f));   // rs1o
    rs[N + v]              = rsqrtf(fmaxf((float)i1, 1.0f));   // rs1i
    rs[2 * (size_t)N + v]  = rsqrtf(fmaxf((float)o2, 1.0f));   // rs2o
    rs[3 * (size_t)N + v]  = rsqrtf(fmaxf((float)i2, 1.0f));   // rs2i
}

// ---- scan phase 1: NODE-MAJOR; element i=(v*NSLICE+q) reads cntD[q][v] ----
__global__ void scan1_kernel(const int* __restrict__ cntD, int* __restrict__ offs,
                             int* __restrict__ bsum, int N, int m) {
    __shared__ int warp_sums[4];
    int t = threadIdx.x;
    int lane = t & 63;
    int wid = t >> 6;
    int base = blockIdx.x * 1024 + t * 4;

    int v4[4];
    int tot = 0;
    #pragma unroll
    for (int j = 0; j < 4; ++j) {
        int i = base + j;
        int d = 0;
        if (i < m) {
            int v = i >> NSLICE_LOG, q = i & (NSLICE - 1);
            d = cntD[(size_t)q * N + v];
        }
        v4[j] = d; tot += d;
    }
    int x = tot;
    #pragma unroll
    for (int off = 1; off < 64; off <<= 1) {
        int y = __shfl_up(x, off, 64);
        if (lane >= off) x += y;
    }
    if (lane == 63) warp_sums[wid] = x;
    __syncthreads();
    int wbase = 0;
    for (int w = 0; w < wid; ++w) wbase += warp_sums[w];
    int run = wbase + x - tot;
    #pragma unroll
    for (int j = 0; j < 4; ++j) {
        int i = base + j;
        if (i < m) offs[i] = run;
        run += v4[j];
    }
    if (t == 255) bsum[blockIdx.x] = run;
}

// ---- scan phase 2 ----
__global__ void scan2_kernel(int* __restrict__ bsum, int* __restrict__ offs, int nb, int m) {
    int lane = threadIdx.x;
    int run = 0;
    for (int base = 0; base < nb; base += 64) {
        int i = base + lane;
        int v = (i < nb) ? bsum[i] : 0;
        int x = v;
        #pragma unroll
        for (int off = 1; off < 64; off <<= 1) {
            int y = __shfl_up(x, off, 64);
            if (lane >= off) x += y;
        }
        if (i < nb) bsum[i] = run + x - v;
        run += __shfl(x, 63, 64);
    }
    if (lane == 0) offs[m] = run;
}

// ---- scan phase 3 ----
__global__ void scan3_kernel(int* __restrict__ offs, const int* __restrict__ bsum, int m) {
    int base = blockIdx.x * 1024 + threadIdx.x * 4;
    int add = bsum[blockIdx.x];
    #pragma unroll
    for (int j = 0; j < 4; ++j) {
        int i = base + j;
        if (i < m) offs[i] += add;
    }
}

// ---- CSR fill: LDS cursors, zero global atomics, 4B entries (src only) ----
__global__ void fill_kernel(const int* __restrict__ s1, const int* __restrict__ d1,
                            const int* __restrict__ s2, const int* __restrict__ d2,
                            const int* __restrict__ offs, int* __restrict__ csr,
                            int N, int ne) {
    extern __shared__ int cur[];
    int t = threadIdx.x;
    int lo = blockIdx.x * CHUNKF;
    int q = blockIdx.y;
    int lim = N - lo < CHUNKF ? N - lo : CHUNKF;
    for (int j = t; j < lim; j += 1024)
        cur[j] = offs[(size_t)(lo + j) * NSLICE + q];
    __syncthreads();

    int SL = (2 * ne) / NSLICE;
    int g = q >= (NSLICE / 2);
    const int* src = g ? s2 : s1;
    const int* dst = g ? d2 : d1;
    int base = g ? ne : 0;
    int e0 = q * SL - base;
    int sl4 = SL & ~4095;
    int e1 = e0 + SL;

    for (int i = e0 + t * 4; i < e0 + sl4; i += 4096) {
        int4 d4 = *(const int4*)(dst + i);
        #pragma unroll
        for (int j = 0; j < 4; ++j) {
            int dd = ((const int*)&d4)[j] - lo;
            if ((unsigned)dd < (unsigned)lim) {
                int pos = atomicAdd(&cur[dd], 1);
                csr[pos] = src[i + j];
            }
        }
    }
    for (int i = e0 + sl4 + t; i < e1; i += 1024) {
        int dd = dst[i] - lo;
        if ((unsigned)dd < (unsigned)lim) {
            int pos = atomicAdd(&cur[dd], 1);
            csr[pos] = src[i];
        }
    }
}

// ---- W convert+transpose, both weights in one launch ----
__global__ void wconv2_kernel(const float* __restrict__ W1, const float* __restrict__ W2,
                              ushort_t* __restrict__ Wt1, ushort_t* __restrict__ Wt2) {
    int tid = blockIdx.x * 256 + threadIdx.x;
    if (tid < 128 * 128) {
        int ncol = tid / 128, k = tid % 128;
        Wt1[tid] = f2b(W1[(size_t)k * 128 + ncol]);
    } else if (tid < 128 * 128 + 64 * 128) {
        int t2 = tid - 128 * 128;
        int ncol = t2 / 128, k = t2 % 128;
        Wt2[t2] = f2b(W2[(size_t)k * 64 + ncol]);
    }
}

// ---- MFMA GEMM: Y[n,NOUT](bf16) = X[n,128] @ W ----
template<int NOUT, bool F32IN>
__global__ __launch_bounds__(256) void mfma_gemm_kernel(const void* __restrict__ Xv,
                                                        const ushort_t* __restrict__ Wt,
                                                        ushort_t* __restrict__ Y, int n) {
    constexpr int CT = NOUT / 16;
    const int lane = threadIdx.x & 63;
    const int wv = threadIdx.x >> 6;
    const int row0 = blockIdx.x * 64 + wv * 16;
    const int arow = row0 + (lane & 15);
    const int arc = arow < n ? arow : (n - 1);

    f32x4 acc[CT];
    #pragma unroll
    for (int ct = 0; ct < CT; ++ct) acc[ct] = (f32x4)(0.f);

    #pragma unroll
    for (int kk = 0; kk < 4; ++kk) {
        const int k0 = kk * 32 + (lane >> 4) * 8;
        bf16x8 a;
        if (F32IN) {
            const float* xp = (const float*)Xv + (size_t)arc * 128 + k0;
            float4 u0 = *(const float4*)xp;
            float4 u1 = *(const float4*)(xp + 4);
            a[0] = (short)f2b(u0.x); a[1] = (short)f2b(u0.y);
            a[2] = (short)f2b(u0.z); a[3] = (short)f2b(u0.w);
            a[4] = (short)f2b(u1.x); a[5] = (short)f2b(u1.y);
            a[6] = (short)f2b(u1.z); a[7] = (short)f2b(u1.w);
        } else {
            a = *(const bf16x8*)((const ushort_t*)Xv + (size_t)arc * 128 + k0);
        }
        #pragma unroll
        for (int ct = 0; ct < CT; ++ct) {
            bf16x8 b = *(const bf16x8*)(Wt + (size_t)(ct * 16 + (lane & 15)) * 128 + k0);
            acc[ct] = __builtin_amdgcn_mfma_f32_16x16x32_bf16(a, b, acc[ct], 0, 0, 0);
        }
    }

    const int orow0 = row0 + (lane >> 4) * 4;
    const int col = lane & 15;
    #pragma unroll
    for (int ct = 0; ct < CT; ++ct) {
        #pragma unroll
        for (int r = 0; r < 4; ++r) {
            int row = orow0 + r;
            if (row < n) Y[(size_t)row * NOUT + ct * 16 + col] = f2b(acc[ct][r]);
        }
    }
}

// ==== agg D=128: HALF-WAVE per edge (32 lanes x uint2 = 256B row) ====
// 8-deep batch = 16 edges in flight; masked final batch per segment.
__device__ __forceinline__ void consume128(const int* __restrict__ csr,
                                           const float* __restrict__ rso,
                                           const ushort_t* __restrict__ V,
                                           int hl, int half, int a, int b,
                                           float& acc0, float& acc1, float& acc2, float& acc3) {
    int e = a;
    for (; e + 16 <= b; e += 16) {
        int sv[8]; float wv[8]; uint2 uv[8];
        #pragma unroll
        for (int j = 0; j < 8; ++j) sv[j] = csr[e + 2 * j + half];
        #pragma unroll
        for (int j = 0; j < 8; ++j) wv[j] = rso[sv[j]];
        #pragma unroll
        for (int j = 0; j < 8; ++j)
            uv[j] = ((const uint2*)(V + (size_t)sv[j] * 128))[hl];
        #pragma unroll
        for (int j = 0; j < 8; ++j) {
            acc0 += wv[j] * b2f_lo(uv[j].x); acc1 += wv[j] * b2f_hi(uv[j].x);
            acc2 += wv[j] * b2f_lo(uv[j].y); acc3 += wv[j] * b2f_hi(uv[j].y);
        }
    }
    if (e < b) {   // masked batch over remaining 1..15 edges
        int sv[8]; float wv[8]; uint2 uv[8];
        #pragma unroll
        for (int j = 0; j < 8; ++j) {
            int idx = e + 2 * j + half;
            bool ok = idx < b;
            sv[j] = csr[ok ? idx : e];
            wv[j] = ok ? 0.f : 0.f;   // placeholder; set below to keep loads first
        }
        #pragma unroll
        for (int j = 0; j < 8; ++j) {
            int idx = e + 2 * j + half;
            wv[j] = (idx < b) ? rso[sv[j]] : 0.f;
        }
        #pragma unroll
        for (int j = 0; j < 8; ++j)
            uv[j] = ((const uint2*)(V + (size_t)sv[j] * 128))[hl];
        #pragma unroll
        for (int j = 0; j < 8; ++j) {
            acc0 += wv[j] * b2f_lo(uv[j].x); acc1 += wv[j] * b2f_hi(uv[j].x);
            acc2 += wv[j] * b2f_lo(uv[j].y); acc3 += wv[j] * b2f_hi(uv[j].y);
        }
    }
}

__global__ void agg128_kernel(const ushort_t* __restrict__ V, const int* __restrict__ offs,
                              const int* __restrict__ csr, const float* __restrict__ rs,
                              const float* __restrict__ bias, const float* __restrict__ attn,
                              uint_t* __restrict__ out, int n) {
    int wid = (int)(((size_t)blockIdx.x * blockDim.x + threadIdx.x) >> 6);
    int lane = threadIdx.x & 63;
    int half = lane >> 5;
    int hl = lane & 31;
    if (wid >= n) return;
    int e0 = offs[(size_t)wid << NSLICE_LOG];
    int eb = offs[((size_t)wid << NSLICE_LOG) + 16];
    int e1 = offs[((size_t)wid << NSLICE_LOG) + NSLICE];

    float s10 = 0.f, s11 = 0.f, s12 = 0.f, s13 = 0.f;
    float s20 = 0.f, s21 = 0.f, s22 = 0.f, s23 = 0.f;
    consume128(csr, rs, V, hl, half, e0, eb, s10, s11, s12, s13);                 // graph 1
    consume128(csr, rs + 2 * (size_t)n, V, hl, half, eb, e1, s20, s21, s22, s23); // graph 2

    float f1 = attn[0] * rs[(size_t)n + wid];
    float f2 = attn[1] * rs[3 * (size_t)n + wid];
    float c0 = f1 * s10 + f2 * s20;
    float c1 = f1 * s11 + f2 * s21;
    float c2 = f1 * s12 + f2 * s22;
    float c3 = f1 * s13 + f2 * s23;
    c0 += __shfl_xor(c0, 32, 64);
    c1 += __shfl_xor(c1, 32, 64);
    c2 += __shfl_xor(c2, 32, 64);
    c3 += __shfl_xor(c3, 32, 64);

    if (half == 0) {
        float bs = attn[0] + attn[1];
        float4 bb = ((const float4*)bias)[hl];
        uint2 o;
        o.x = (uint_t)f2b(c0 + bs * bb.x) | ((uint_t)f2b(c1 + bs * bb.y) << 16);
        o.y = (uint_t)f2b(c2 + bs * bb.z) | ((uint_t)f2b(c3 + bs * bb.w) << 16);
        ((uint2*)(out + (size_t)wid * 64))[hl] = o;
    }
}

// ==== agg D=64: QUARTER-WAVE per edge (16 lanes x uint2 = 128B row) ====
// 8-deep batch = 32 edges in flight; masked final batch per segment.
__device__ __forceinline__ void consume64(const int* __restrict__ csr,
                                          const float* __restrict__ rso,
                                          const ushort_t* __restrict__ V,
                                          int ql, int quarter, int a, int b,
                                          float& acc0, float& acc1, float& acc2, float& acc3) {
    int e = a;
    for (; e + 32 <= b; e += 32) {
        int sv[8]; float wv[8]; uint2 uv[8];
        #pragma unroll
        for (int j = 0; j < 8; ++j) sv[j] = csr[e + 4 * j + quarter];
        #pragma unroll
        for (int j = 0; j < 8; ++j) wv[j] = rso[sv[j]];
        #pragma unroll
        for (int j = 0; j < 8; ++j)
            uv[j] = ((const uint2*)(V + (size_t)sv[j] * 64))[ql];
        #pragma unroll
        for (int j = 0; j < 8; ++j) {
            acc0 += wv[j] * b2f_lo(uv[j].x); acc1 += wv[j] * b2f_hi(uv[j].x);
            acc2 += wv[j] * b2f_lo(uv[j].y); acc3 += wv[j] * b2f_hi(uv[j].y);
        }
    }
    if (e < b) {   // masked batch over remaining 1..31 edges
        int sv[8]; float wv[8]; uint2 uv[8];
        #pragma unroll
        for (int j = 0; j < 8; ++j) {
            int idx = e + 4 * j + quarter;
            sv[j] = csr[idx < b ? idx : e];
        }
        #pragma unroll
        for (int j = 0; j < 8; ++j) {
            int idx = e + 4 * j + quarter;
            wv[j] = (idx < b) ? rso[sv[j]] : 0.f;
        }
        #pragma unroll
        for (int j = 0; j < 8; ++j)
            uv[j] = ((const uint2*)(V + (size_t)sv[j] * 64))[ql];
        #pragma unroll
        for (int j = 0; j < 8; ++j) {
            acc0 += wv[j] * b2f_lo(uv[j].x); acc1 += wv[j] * b2f_hi(uv[j].x);
            acc2 += wv[j] * b2f_lo(uv[j].y); acc3 += wv[j] * b2f_hi(uv[j].y);
        }
    }
}

__global__ void agg64_kernel(const ushort_t* __restrict__ V, const int* __restrict__ offs,
                             const int* __restrict__ csr, const float* __restrict__ rs,
                             const float* __restrict__ bias, const float* __restrict__ attn,
                             float* __restrict__ out, int n) {
    int wid = (int)(((size_t)blockIdx.x * blockDim.x + threadIdx.x) >> 6);
    int lane = threadIdx.x & 63;
    int quarter = lane >> 4;
    int ql = lane & 15;
    if (wid >= n) return;
    int e0 = offs[(size_t)wid << NSLICE_LOG];
    int eb = offs[((size_t)wid << NSLICE_LOG) + 16];
    int e1 = offs[((size_t)wid << NSLICE_LOG) + NSLICE];

    float s10 = 0.f, s11 = 0.f, s12 = 0.f, s13 = 0.f;
    float s20 = 0.f, s21 = 0.f, s22 = 0.f, s23 = 0.f;
    consume64(csr, rs, V, ql, quarter, e0, eb, s10, s11, s12, s13);                 // graph 1
    consume64(csr, rs + 2 * (size_t)n, V, ql, quarter, eb, e1, s20, s21, s22, s23); // graph 2

    float f1 = attn[0] * rs[(size_t)n + wid];
    float f2 = attn[1] * rs[3 * (size_t)n + wid];
    float c0 = f1 * s10 + f2 * s20;
    float c1 = f1 * s11 + f2 * s21;
    float c2 = f1 * s12 + f2 * s22;
    float c3 = f1 * s13 + f2 * s23;
    c0 += __shfl_xor(c0, 16, 64); c0 += __shfl_xor(c0, 32, 64);
    c1 += __shfl_xor(c1, 16, 64); c1 += __shfl_xor(c1, 32, 64);
    c2 += __shfl_xor(c2, 16, 64); c2 += __shfl_xor(c2, 32, 64);
    c3 += __shfl_xor(c3, 16, 64); c3 += __shfl_xor(c3, 32, 64);

    if (quarter == 0) {
        float bs = attn[0] + attn[1];
        float4 bb = ((const float4*)bias)[ql];
        float4 o = make_float4(c0 + bs * bb.x, c1 + bs * bb.y,
                               c2 + bs * bb.z, c3 + bs * bb.w);
        ((float4*)(out + (size_t)wid * 64))[ql] = o;
    }
}

extern "C" void kernel_launch(void* const* d_in, const int* in_sizes, int n_in,
                              void* d_out, int out_size, void* d_ws, size_t ws_size,
                              hipStream_t stream) {
    const float* feat = (const float*)d_in[0];
    const int* src1   = (const int*)d_in[1];
    const int* dst1   = (const int*)d_in[2];
    const int* src2   = (const int*)d_in[3];
    const int* dst2   = (const int*)d_in[4];
    const float* attn = (const float*)d_in[5];
    const float* W1   = (const float*)d_in[6];
    const float* b1   = (const float*)d_in[7];
    const float* W2   = (const float*)d_in[8];
    const float* b2   = (const float*)d_in[9];
    float* out = (float*)d_out;

    const int N  = in_sizes[0] / DINF;        // 50000
    const int NE = in_sizes[1];               // 600000
    const int M  = NSLICE * N;                // offs length (1.6M), node-major
    const int NB2 = (M + 1023) / 1024;        // scan blocks

    // workspace layout:
    // Wt1 | Wt2 | A bf16[N*128] | B bf16[N*128] | C bf16[N*64] |
    // offs[M+1] | cntS[M] | cntD[M] | rs f32[4N] | bsum[NB2]
    // csr (int[2NE] = 4.8 MB) OVERLAYS cntS (6.4 MB): counts dead after scan1.
    ushort_t* Wt1 = (ushort_t*)d_ws;
    ushort_t* Wt2 = Wt1 + 128 * 128;
    ushort_t* A   = Wt2 + 64 * 128;
    ushort_t* B   = A + (size_t)N * DHID;
    ushort_t* C   = B + (size_t)N * DHID;
    int* offs   = (int*)(C + (size_t)N * DOUTF);
    int* cntS   = offs + (M + 1);
    int* cntD   = cntS + M;
    float* rs   = (float*)(cntD + M);
    int* bsum   = (int*)(rs + 4 * (size_t)N);
    int* csr    = cntS;                       // overlay

    wconv2_kernel<<<(128 * 128 + 64 * 128 + 255) / 256, 256, 0, stream>>>(W1, W2, Wt1, Wt2);

    cnt_kernel<<<dim3(NCHUNKC, NSLICE, 2), 1024, CHUNKC * sizeof(int), stream>>>(
        src1, dst1, src2, dst2, cntS, cntD, N, NE);

    degred_kernel<<<(N + 255) / 256, 256, 0, stream>>>(cntS, cntD, rs, N);

    scan1_kernel<<<NB2, 256, 0, stream>>>(cntD, offs, bsum, N, M);
    scan2_kernel<<<1, 64, 0, stream>>>(bsum, offs, NB2, M);
    scan3_kernel<<<NB2, 256, 0, stream>>>(offs, bsum, M);

    fill_kernel<<<dim3(NCHUNKF, NSLICE), 1024, CHUNKF * sizeof(int), stream>>>(
        src1, dst1, src2, dst2, offs, csr, N, NE);

    int gb = (N + 63) / 64;
    int ab = (N + 3) / 4;
    // layer 1: A = bf16(feat @ W1) ; B = bf16(agg(A))
    mfma_gemm_kernel<DHID, true><<<gb, 256, 0, stream>>>(feat, Wt1, A, N);
    agg128_kernel<<<ab, 256, 0, stream>>>(A, offs, csr, rs, b1, attn, (uint_t*)B, N);

    // layer 2: C = bf16(B @ W2) ; out = agg(C)  (f32)
    mfma_gemm_kernel<DOUTF, false><<<gb, 256, 0, stream>>>(B, Wt2, C, N);
    agg64_kernel<<<ab, 256, 0, stream>>>(C, offs, csr, rs, b2, attn, out, N);
}

// Round 15
// 202.479 us; speedup vs baseline: 1.1099x; 1.0008x over previous
//
#include <hip/hip_runtime.h>

#define DINF 128
#define DHID 128
#define DOUTF 64

#define NSLICE 32       // edge slices (16 per graph); CSR node-major, slice-minor
#define NSLICE_LOG 5
#define CHUNKC 12544    // cnt histogram chunk (49 KB LDS)
#define NCHUNKC 4
#define CHUNKF 3136     // fill cursor chunk (12.5 KB LDS)
#define NCHUNKF 16

typedef unsigned short ushort_t;
typedef unsigned int uint_t;
typedef __attribute__((ext_vector_type(8))) short bf16x8;
typedef __attribute__((ext_vector_type(4))) float f32x4;

__device__ __forceinline__ ushort_t f2b(float x) {   // f32 -> bf16 RNE
    uint_t u = __float_as_uint(x);
    u += 0x7fffu + ((u >> 16) & 1u);
    return (ushort_t)(u >> 16);
}
__device__ __forceinline__ float b2f_lo(uint_t u) { return __uint_as_float(u << 16); }
__device__ __forceinline__ float b2f_hi(uint_t u) { return __uint_as_float(u & 0xffff0000u); }

// ---- per-(slice, node) histograms of src and dst; plain stores only ----
__global__ void cnt_kernel(const int* __restrict__ s1, const int* __restrict__ d1,
                           const int* __restrict__ s2, const int* __restrict__ d2,
                           int* __restrict__ cntS, int* __restrict__ cntD, int N, int ne) {
    extern __shared__ int h[];
    int t = threadIdx.x;
    for (int j = t; j < CHUNKC; j += 1024) h[j] = 0;
    __syncthreads();

    int lo = blockIdx.x * CHUNKC;
    int q = blockIdx.y;
    bool isSrc = blockIdx.z == 0;
    int SL = (2 * ne) / NSLICE;
    int g = q >= (NSLICE / 2);
    const int* p = g ? (isSrc ? s2 : d2) : (isSrc ? s1 : d1);
    int base = g ? ne : 0;
    int e0 = q * SL - base;
    int e1 = e0 + SL;
    for (int i = e0 + t; i < e1; i += 1024) {
        int v = p[i] - lo;
        if ((unsigned)v < (unsigned)CHUNKC) atomicAdd(&h[v], 1);
    }
    __syncthreads();

    int* c = (isSrc ? cntS : cntD) + (size_t)q * N;
    for (int j = t; j < CHUNKC; j += 1024) {
        int node = lo + j;
        if (node < N) c[node] = h[j];
    }
}

// ---- degrees from slice-count sums; store rsqrt(max(deg,1)) ----
__global__ void degred_kernel(const int* __restrict__ cntS, const int* __restrict__ cntD,
                              float* __restrict__ rs, int N) {
    int v = blockIdx.x * 256 + threadIdx.x;
    if (v >= N) return;
    int o1 = 0, i1 = 0, o2 = 0, i2 = 0;
    #pragma unroll
    for (int q = 0; q < NSLICE / 2; ++q) {
        o1 += cntS[(size_t)q * N + v];
        i1 += cntD[(size_t)q * N + v];
    }
    #pragma unroll
    for (int q = NSLICE / 2; q < NSLICE; ++q) {
        o2 += cntS[(size_t)q * N + v];
        i2 += cntD[(size_t)q * N + v];
    }
    rs[v]                  = rsqrtf(fmaxf((float)o1, 1.0f));   // rs1o
    rs[N + v]              = rsqrtf(fmaxf((float)i1, 1.0f));   // rs1i
    rs[2 * (size_t)N + v]  = rsqrtf(fmaxf((float)o2, 1.0f));   // rs2o
    rs[3 * (size_t)N + v]  = rsqrtf(fmaxf((float)i2, 1.0f));   // rs2i
}

// ---- scan phase 1: NODE-MAJOR; element i=(v*NSLICE+q) reads cntD[q][v] ----
__global__ void scan1_kernel(const int* __restrict__ cntD, int* __restrict__ offs,
                             int* __restrict__ bsum, int N, int m) {
    __shared__ int warp_sums[4];
    int t = threadIdx.x;
    int lane = t & 63;
    int wid = t >> 6;
    int base = blockIdx.x * 1024 + t * 4;

    int v4[4];
    int tot = 0;
    #pragma unroll
    for (int j = 0; j < 4; ++j) {
        int i = base + j;
        int d = 0;
        if (i < m) {
            int v = i >> NSLICE_LOG, q = i & (NSLICE - 1);
            d = cntD[(size_t)q * N + v];
        }
        v4[j] = d; tot += d;
    }
    int x = tot;
    #pragma unroll
    for (int off = 1; off < 64; off <<= 1) {
        int y = __shfl_up(x, off, 64);
        if (lane >= off) x += y;
    }
    if (lane == 63) warp_sums[wid] = x;
    __syncthreads();
    int wbase = 0;
    for (int w = 0; w < wid; ++w) wbase += warp_sums[w];
    int run = wbase + x - tot;
    #pragma unroll
    for (int j = 0; j < 4; ++j) {
        int i = base + j;
        if (i < m) offs[i] = run;
        run += v4[j];
    }
    if (t == 255) bsum[blockIdx.x] = run;
}

// ---- scan phase 2: also writes the grand total into nodeoff[N].x ----
__global__ void scan2_kernel(int* __restrict__ bsum, int* __restrict__ offs,
                             int* __restrict__ noff, int nb, int m) {
    int lane = threadIdx.x;
    int run = 0;
    for (int base = 0; base < nb; base += 64) {
        int i = base + lane;
        int v = (i < nb) ? bsum[i] : 0;
        int x = v;
        #pragma unroll
        for (int off = 1; off < 64; off <<= 1) {
            int y = __shfl_up(x, off, 64);
            if (lane >= off) x += y;
        }
        if (i < nb) bsum[i] = run + x - v;
        run += __shfl(x, 63, 64);
    }
    if (lane == 0) {
        offs[m] = run;
        noff[(size_t)(m >> NSLICE_LOG) * 2] = run;       // nodeoff[N].x
        noff[(size_t)(m >> NSLICE_LOG) * 2 + 1] = run;   // nodeoff[N].y (unused)
    }
}

// ---- scan phase 3: add block prefix; emit compact per-node {e0, eb} ----
__global__ void scan3_kernel(int* __restrict__ offs, const int* __restrict__ bsum,
                             int* __restrict__ noff, int m) {
    int base = blockIdx.x * 1024 + threadIdx.x * 4;
    int add = bsum[blockIdx.x];
    #pragma unroll
    for (int j = 0; j < 4; ++j) {
        int i = base + j;
        if (i < m) {
            int o = offs[i] + add;
            offs[i] = o;
            int q = i & (NSLICE - 1);
            if (q == 0)  noff[(size_t)(i >> NSLICE_LOG) * 2] = o;       // e0
            if (q == 16) noff[(size_t)(i >> NSLICE_LOG) * 2 + 1] = o;   // eb
        }
    }
}

// ---- CSR fill: LDS cursors, zero global atomics, 2B entries (src as u16) ----
__global__ void fill_kernel(const int* __restrict__ s1, const int* __restrict__ d1,
                            const int* __restrict__ s2, const int* __restrict__ d2,
                            const int* __restrict__ offs, ushort_t* __restrict__ csr,
                            int N, int ne) {
    extern __shared__ int cur[];
    int t = threadIdx.x;
    int lo = blockIdx.x * CHUNKF;
    int q = blockIdx.y;
    int lim = N - lo < CHUNKF ? N - lo : CHUNKF;
    for (int j = t; j < lim; j += 1024)
        cur[j] = offs[(size_t)(lo + j) * NSLICE + q];
    __syncthreads();

    int SL = (2 * ne) / NSLICE;
    int g = q >= (NSLICE / 2);
    const int* src = g ? s2 : s1;
    const int* dst = g ? d2 : d1;
    int base = g ? ne : 0;
    int e0 = q * SL - base;
    int sl4 = SL & ~4095;
    int e1 = e0 + SL;

    for (int i = e0 + t * 4; i < e0 + sl4; i += 4096) {
        int4 d4 = *(const int4*)(dst + i);
        #pragma unroll
        for (int j = 0; j < 4; ++j) {
            int dd = ((const int*)&d4)[j] - lo;
            if ((unsigned)dd < (unsigned)lim) {
                int pos = atomicAdd(&cur[dd], 1);
                csr[pos] = (ushort_t)src[i + j];
            }
        }
    }
    for (int i = e0 + sl4 + t; i < e1; i += 1024) {
        int dd = dst[i] - lo;
        if ((unsigned)dd < (unsigned)lim) {
            int pos = atomicAdd(&cur[dd], 1);
            csr[pos] = (ushort_t)src[i];
        }
    }
}

// ---- W convert+transpose, both weights in one launch ----
__global__ void wconv2_kernel(const float* __restrict__ W1, const float* __restrict__ W2,
                              ushort_t* __restrict__ Wt1, ushort_t* __restrict__ Wt2) {
    int tid = blockIdx.x * 256 + threadIdx.x;
    if (tid < 128 * 128) {
        int ncol = tid / 128, k = tid % 128;
        Wt1[tid] = f2b(W1[(size_t)k * 128 + ncol]);
    } else if (tid < 128 * 128 + 64 * 128) {
        int t2 = tid - 128 * 128;
        int ncol = t2 / 128, k = t2 % 128;
        Wt2[t2] = f2b(W2[(size_t)k * 64 + ncol]);
    }
}

// ---- MFMA GEMM: Y[n,NOUT](bf16) = X[n,128] @ W ----
template<int NOUT, bool F32IN>
__global__ __launch_bounds__(256) void mfma_gemm_kernel(const void* __restrict__ Xv,
                                                        const ushort_t* __restrict__ Wt,
                                                        ushort_t* __restrict__ Y, int n) {
    constexpr int CT = NOUT / 16;
    const int lane = threadIdx.x & 63;
    const int wv = threadIdx.x >> 6;
    const int row0 = blockIdx.x * 64 + wv * 16;
    const int arow = row0 + (lane & 15);
    const int arc = arow < n ? arow : (n - 1);

    f32x4 acc[CT];
    #pragma unroll
    for (int ct = 0; ct < CT; ++ct) acc[ct] = (f32x4)(0.f);

    #pragma unroll
    for (int kk = 0; kk < 4; ++kk) {
        const int k0 = kk * 32 + (lane >> 4) * 8;
        bf16x8 a;
        if (F32IN) {
            const float* xp = (const float*)Xv + (size_t)arc * 128 + k0;
            float4 u0 = *(const float4*)xp;
            float4 u1 = *(const float4*)(xp + 4);
            a[0] = (short)f2b(u0.x); a[1] = (short)f2b(u0.y);
            a[2] = (short)f2b(u0.z); a[3] = (short)f2b(u0.w);
            a[4] = (short)f2b(u1.x); a[5] = (short)f2b(u1.y);
            a[6] = (short)f2b(u1.z); a[7] = (short)f2b(u1.w);
        } else {
            a = *(const bf16x8*)((const ushort_t*)Xv + (size_t)arc * 128 + k0);
        }
        #pragma unroll
        for (int ct = 0; ct < CT; ++ct) {
            bf16x8 b = *(const bf16x8*)(Wt + (size_t)(ct * 16 + (lane & 15)) * 128 + k0);
            acc[ct] = __builtin_amdgcn_mfma_f32_16x16x32_bf16(a, b, acc[ct], 0, 0, 0);
        }
    }

    const int orow0 = row0 + (lane >> 4) * 4;
    const int col = lane & 15;
    #pragma unroll
    for (int ct = 0; ct < CT; ++ct) {
        #pragma unroll
        for (int r = 0; r < 4; ++r) {
            int row = orow0 + r;
            if (row < n) Y[(size_t)row * NOUT + ct * 16 + col] = f2b(acc[ct][r]);
        }
    }
}

// ==== agg D=128: HALF-WAVE per edge (32 lanes x uint2 = 256B row) ====
__device__ __forceinline__ void consume128(const ushort_t* __restrict__ csr,
                                           const float* __restrict__ rso,
                                           const ushort_t* __restrict__ V,
                                           int hl, int half, int a, int b,
                                           float& acc0, float& acc1, float& acc2, float& acc3) {
    int e = a;
    for (; e + 16 <= b; e += 16) {
        int sv[8]; float wv[8]; uint2 uv[8];
        #pragma unroll
        for (int j = 0; j < 8; ++j) sv[j] = csr[e + 2 * j + half];
        #pragma unroll
        for (int j = 0; j < 8; ++j) wv[j] = rso[sv[j]];
        #pragma unroll
        for (int j = 0; j < 8; ++j)
            uv[j] = ((const uint2*)(V + (size_t)sv[j] * 128))[hl];
        #pragma unroll
        for (int j = 0; j < 8; ++j) {
            acc0 += wv[j] * b2f_lo(uv[j].x); acc1 += wv[j] * b2f_hi(uv[j].x);
            acc2 += wv[j] * b2f_lo(uv[j].y); acc3 += wv[j] * b2f_hi(uv[j].y);
        }
    }
    if (e < b) {   // masked batch over remaining 1..15 edges
        int sv[8]; float wv[8]; uint2 uv[8];
        #pragma unroll
        for (int j = 0; j < 8; ++j) {
            int idx = e + 2 * j + half;
            sv[j] = csr[idx < b ? idx : e];
        }
        #pragma unroll
        for (int j = 0; j < 8; ++j) {
            int idx = e + 2 * j + half;
            wv[j] = (idx < b) ? rso[sv[j]] : 0.f;
        }
        #pragma unroll
        for (int j = 0; j < 8; ++j)
            uv[j] = ((const uint2*)(V + (size_t)sv[j] * 128))[hl];
        #pragma unroll
        for (int j = 0; j < 8; ++j) {
            acc0 += wv[j] * b2f_lo(uv[j].x); acc1 += wv[j] * b2f_hi(uv[j].x);
            acc2 += wv[j] * b2f_lo(uv[j].y); acc3 += wv[j] * b2f_hi(uv[j].y);
        }
    }
}

__global__ void agg128_kernel(const ushort_t* __restrict__ V, const int2* __restrict__ noff,
                              const ushort_t* __restrict__ csr, const float* __restrict__ rs,
                              const float* __restrict__ bias, const float* __restrict__ attn,
                              uint_t* __restrict__ out, int n) {
    int wid = (int)(((size_t)blockIdx.x * blockDim.x + threadIdx.x) >> 6);
    int lane = threadIdx.x & 63;
    int half = lane >> 5;
    int hl = lane & 31;
    if (wid >= n) return;
    int2 nv = noff[wid];
    int e0 = nv.x, eb = nv.y;
    int e1 = noff[wid + 1].x;

    float s10 = 0.f, s11 = 0.f, s12 = 0.f, s13 = 0.f;
    float s20 = 0.f, s21 = 0.f, s22 = 0.f, s23 = 0.f;
    consume128(csr, rs, V, hl, half, e0, eb, s10, s11, s12, s13);                 // graph 1
    consume128(csr, rs + 2 * (size_t)n, V, hl, half, eb, e1, s20, s21, s22, s23); // graph 2

    float f1 = attn[0] * rs[(size_t)n + wid];
    float f2 = attn[1] * rs[3 * (size_t)n + wid];
    float c0 = f1 * s10 + f2 * s20;
    float c1 = f1 * s11 + f2 * s21;
    float c2 = f1 * s12 + f2 * s22;
    float c3 = f1 * s13 + f2 * s23;
    c0 += __shfl_xor(c0, 32, 64);
    c1 += __shfl_xor(c1, 32, 64);
    c2 += __shfl_xor(c2, 32, 64);
    c3 += __shfl_xor(c3, 32, 64);

    if (half == 0) {
        float bs = attn[0] + attn[1];
        float4 bb = ((const float4*)bias)[hl];
        uint2 o;
        o.x = (uint_t)f2b(c0 + bs * bb.x) | ((uint_t)f2b(c1 + bs * bb.y) << 16);
        o.y = (uint_t)f2b(c2 + bs * bb.z) | ((uint_t)f2b(c3 + bs * bb.w) << 16);
        ((uint2*)(out + (size_t)wid * 64))[hl] = o;
    }
}

// ==== agg D=64: QUARTER-WAVE per edge (16 lanes x uint2 = 128B row) ====
__device__ __forceinline__ void consume64(const ushort_t* __restrict__ csr,
                                          const float* __restrict__ rso,
                                          const ushort_t* __restrict__ V,
                                          int ql, int quarter, int a, int b,
                                          float& acc0, float& acc1, float& acc2, float& acc3) {
    int e = a;
    for (; e + 32 <= b; e += 32) {
        int sv[8]; float wv[8]; uint2 uv[8];
        #pragma unroll
        for (int j = 0; j < 8; ++j) sv[j] = csr[e + 4 * j + quarter];
        #pragma unroll
        for (int j = 0; j < 8; ++j) wv[j] = rso[sv[j]];
        #pragma unroll
        for (int j = 0; j < 8; ++j)
            uv[j] = ((const uint2*)(V + (size_t)sv[j] * 64))[ql];
        #pragma unroll
        for (int j = 0; j < 8; ++j) {
            acc0 += wv[j] * b2f_lo(uv[j].x); acc1 += wv[j] * b2f_hi(uv[j].x);
            acc2 += wv[j] * b2f_lo(uv[j].y); acc3 += wv[j] * b2f_hi(uv[j].y);
        }
    }
    if (e < b) {   // masked batch over remaining 1..31 edges
        int sv[8]; float wv[8]; uint2 uv[8];
        #pragma unroll
        for (int j = 0; j < 8; ++j) {
            int idx = e + 4 * j + quarter;
            sv[j] = csr[idx < b ? idx : e];
        }
        #pragma unroll
        for (int j = 0; j < 8; ++j) {
            int idx = e + 4 * j + quarter;
            wv[j] = (idx < b) ? rso[sv[j]] : 0.f;
        }
        #pragma unroll
        for (int j = 0; j < 8; ++j)
            uv[j] = ((const uint2*)(V + (size_t)sv[j] * 64))[ql];
        #pragma unroll
        for (int j = 0; j < 8; ++j) {
            acc0 += wv[j] * b2f_lo(uv[j].x); acc1 += wv[j] * b2f_hi(uv[j].x);
            acc2 += wv[j] * b2f_lo(uv[j].y); acc3 += wv[j] * b2f_hi(uv[j].y);
        }
    }
}

__global__ void agg64_kernel(const ushort_t* __restrict__ V, const int2* __restrict__ noff,
                             const ushort_t* __restrict__ csr, const float* __restrict__ rs,
                             const float* __restrict__ bias, const float* __restrict__ attn,
                             float* __restrict__ out, int n) {
    int wid = (int)(((size_t)blockIdx.x * blockDim.x + threadIdx.x) >> 6);
    int lane = threadIdx.x & 63;
    int quarter = lane >> 4;
    int ql = lane & 15;
    if (wid >= n) return;
    int2 nv = noff[wid];
    int e0 = nv.x, eb = nv.y;
    int e1 = noff[wid + 1].x;

    float s10 = 0.f, s11 = 0.f, s12 = 0.f, s13 = 0.f;
    float s20 = 0.f, s21 = 0.f, s22 = 0.f, s23 = 0.f;
    consume64(csr, rs, V, ql, quarter, e0, eb, s10, s11, s12, s13);                 // graph 1
    consume64(csr, rs + 2 * (size_t)n, V, ql, quarter, eb, e1, s20, s21, s22, s23); // graph 2

    float f1 = attn[0] * rs[(size_t)n + wid];
    float f2 = attn[1] * rs[3 * (size_t)n + wid];
    float c0 = f1 * s10 + f2 * s20;
    float c1 = f1 * s11 + f2 * s21;
    float c2 = f1 * s12 + f2 * s22;
    float c3 = f1 * s13 + f2 * s23;
    c0 += __shfl_xor(c0, 16, 64); c0 += __shfl_xor(c0, 32, 64);
    c1 += __shfl_xor(c1, 16, 64); c1 += __shfl_xor(c1, 32, 64);
    c2 += __shfl_xor(c2, 16, 64); c2 += __shfl_xor(c2, 32, 64);
    c3 += __shfl_xor(c3, 16, 64); c3 += __shfl_xor(c3, 32, 64);

    if (quarter == 0) {
        float bs = attn[0] + attn[1];
        float4 bb = ((const float4*)bias)[ql];
        float4 o = make_float4(c0 + bs * bb.x, c1 + bs * bb.y,
                               c2 + bs * bb.z, c3 + bs * bb.w);
        ((float4*)(out + (size_t)wid * 64))[ql] = o;
    }
}

extern "C" void kernel_launch(void* const* d_in, const int* in_sizes, int n_in,
                              void* d_out, int out_size, void* d_ws, size_t ws_size,
                              hipStream_t stream) {
    const float* feat = (const float*)d_in[0];
    const int* src1   = (const int*)d_in[1];
    const int* dst1   = (const int*)d_in[2];
    const int* src2   = (const int*)d_in[3];
    const int* dst2   = (const int*)d_in[4];
    const float* attn = (const float*)d_in[5];
    const float* W1   = (const float*)d_in[6];
    const float* b1   = (const float*)d_in[7];
    const float* W2   = (const float*)d_in[8];
    const float* b2   = (const float*)d_in[9];
    float* out = (float*)d_out;

    const int N  = in_sizes[0] / DINF;        // 50000
    const int NE = in_sizes[1];               // 600000
    const int M  = NSLICE * N;                // offs length (1.6M), node-major
    const int NB2 = (M + 1023) / 1024;        // scan blocks

    // workspace layout:
    // Wt1 | Wt2 | A bf16[N*128] | B bf16[N*128] | C bf16[N*64] |
    // offs[M+1] | noff int2[N+1] | cntS[M] | cntD[M] | rs f32[4N] | bsum[NB2]
    // csr (u16[2NE] = 2.4 MB) OVERLAYS cntS (6.4 MB): counts dead after scan1.
    ushort_t* Wt1 = (ushort_t*)d_ws;
    ushort_t* Wt2 = Wt1 + 128 * 128;
    ushort_t* A   = Wt2 + 64 * 128;
    ushort_t* B   = A + (size_t)N * DHID;
    ushort_t* C   = B + (size_t)N * DHID;
    int* offs   = (int*)(C + (size_t)N * DOUTF);
    int* noff   = offs + (M + 1);             // int2[N+1] as int pairs
    int* cntS   = noff + 2 * (N + 1);
    int* cntD   = cntS + M;
    float* rs   = (float*)(cntD + M);
    int* bsum   = (int*)(rs + 4 * (size_t)N);
    ushort_t* csr = (ushort_t*)cntS;          // overlay

    wconv2_kernel<<<(128 * 128 + 64 * 128 + 255) / 256, 256, 0, stream>>>(W1, W2, Wt1, Wt2);

    cnt_kernel<<<dim3(NCHUNKC, NSLICE, 2), 1024, CHUNKC * sizeof(int), stream>>>(
        src1, dst1, src2, dst2, cntS, cntD, N, NE);

    degred_kernel<<<(N + 255) / 256, 256, 0, stream>>>(cntS, cntD, rs, N);

    scan1_kernel<<<NB2, 256, 0, stream>>>(cntD, offs, bsum, N, M);
    scan2_kernel<<<1, 64, 0, stream>>>(bsum, offs, noff, NB2, M);
    scan3_kernel<<<NB2, 256, 0, stream>>>(offs, bsum, noff, M);

    fill_kernel<<<dim3(NCHUNKF, NSLICE), 1024, CHUNKF * sizeof(int), stream>>>(
        src1, dst1, src2, dst2, offs, csr, N, NE);

    int gb = (N + 63) / 64;
    int ab = (N + 3) / 4;
    // layer 1: A = bf16(feat @ W1) ; B = bf16(agg(A))
    mfma_gemm_kernel<DHID, true><<<gb, 256, 0, stream>>>(feat, Wt1, A, N);
    agg128_kernel<<<ab, 256, 0, stream>>>(A, (const int2*)noff, csr, rs, b1, attn, (uint_t*)B, N);

    // layer 2: C = bf16(B @ W2) ; out = agg(C)  (f32)
    mfma_gemm_kernel<DOUTF, false><<<gb, 256, 0, stream>>>(B, Wt2, C, N);
    agg64_kernel<<<ab, 256, 0, stream>>>(C, (const int2*)noff, csr, rs, b2, attn, out, N);
}

// Round 16
// 195.648 us; speedup vs baseline: 1.1487x; 1.0349x over previous
//
#include <hip/hip_runtime.h>

#define DINF 128
#define DHID 128
#define DOUTF 64

#define NSLICE 32       // edge slices (16 per graph); CSR node-major, slice-minor
#define NSLICE_LOG 5
#define CHUNKC 12544    // cnt histogram chunk (49 KB LDS)
#define NCHUNKC 4
#define CHUNKF 6272     // fill cursor chunk (24.5 KB LDS)
#define NCHUNKF 8

typedef unsigned short ushort_t;
typedef unsigned int uint_t;
typedef __attribute__((ext_vector_type(8))) short bf16x8;
typedef __attribute__((ext_vector_type(4))) float f32x4;

__device__ __forceinline__ ushort_t f2b(float x) {   // f32 -> bf16 RNE
    uint_t u = __float_as_uint(x);
    u += 0x7fffu + ((u >> 16) & 1u);
    return (ushort_t)(u >> 16);
}
__device__ __forceinline__ float b2f_lo(uint_t u) { return __uint_as_float(u << 16); }
__device__ __forceinline__ float b2f_hi(uint_t u) { return __uint_as_float(u & 0xffff0000u); }

// ---- per-(slice, node) histograms of src and dst; plain stores, int4 stream ----
__global__ void cnt_kernel(const int* __restrict__ s1, const int* __restrict__ d1,
                           const int* __restrict__ s2, const int* __restrict__ d2,
                           int* __restrict__ cntS, int* __restrict__ cntD, int N, int ne) {
    extern __shared__ int h[];
    int t = threadIdx.x;
    for (int j = t; j < CHUNKC; j += 1024) h[j] = 0;
    __syncthreads();

    int lo = blockIdx.x * CHUNKC;
    int q = blockIdx.y;
    bool isSrc = blockIdx.z == 0;
    int SL = (2 * ne) / NSLICE;           // 37500, %4==0, slice starts 16B-aligned
    int g = q >= (NSLICE / 2);
    const int* p = g ? (isSrc ? s2 : d2) : (isSrc ? s1 : d1);
    int base = g ? ne : 0;
    int e0 = q * SL - base;
    int e1 = e0 + SL;
    for (int i = e0 + t * 4; i + 3 < e1; i += 4096) {
        int4 v4 = *(const int4*)(p + i);
        #pragma unroll
        for (int j = 0; j < 4; ++j) {
            int v = ((const int*)&v4)[j] - lo;
            if ((unsigned)v < (unsigned)CHUNKC) atomicAdd(&h[v], 1);
        }
    }
    __syncthreads();

    int* c = (isSrc ? cntS : cntD) + (size_t)q * N;
    for (int j = t; j < CHUNKC; j += 1024) {
        int node = lo + j;
        if (node < N) c[node] = h[j];
    }
}

// ---- degrees from slice-count sums; store rsqrt(max(deg,1)) ----
__global__ void degred_kernel(const int* __restrict__ cntS, const int* __restrict__ cntD,
                              float* __restrict__ rs, int N) {
    int v = blockIdx.x * 256 + threadIdx.x;
    if (v >= N) return;
    int o1 = 0, i1 = 0, o2 = 0, i2 = 0;
    #pragma unroll
    for (int q = 0; q < NSLICE / 2; ++q) {
        o1 += cntS[(size_t)q * N + v];
        i1 += cntD[(size_t)q * N + v];
    }
    #pragma unroll
    for (int q = NSLICE / 2; q < NSLICE; ++q) {
        o2 += cntS[(size_t)q * N + v];
        i2 += cntD[(size_t)q * N + v];
    }
    rs[v]                  = rsqrtf(fmaxf((float)o1, 1.0f));   // rs1o
    rs[N + v]              = rsqrtf(fmaxf((float)i1, 1.0f));   // rs1i
    rs[2 * (size_t)N + v]  = rsqrtf(fmaxf((float)o2, 1.0f));   // rs2o
    rs[3 * (size_t)N + v]  = rsqrtf(fmaxf((float)i2, 1.0f));   // rs2i
}

// ---- scan phase 1: NODE-MAJOR; element i=(v*NSLICE+q) reads cntD[q][v] ----
__global__ void scan1_kernel(const int* __restrict__ cntD, int* __restrict__ offs,
                             int* __restrict__ bsum, int N, int m) {
    __shared__ int warp_sums[4];
    int t = threadIdx.x;
    int lane = t & 63;
    int wid = t >> 6;
    int base = blockIdx.x * 1024 + t * 4;

    int v4[4];
    int tot = 0;
    #pragma unroll
    for (int j = 0; j < 4; ++j) {
        int i = base + j;
        int d = 0;
        if (i < m) {
            int v = i >> NSLICE_LOG, q = i & (NSLICE - 1);
            d = cntD[(size_t)q * N + v];
        }
        v4[j] = d; tot += d;
    }
    int x = tot;
    #pragma unroll
    for (int off = 1; off < 64; off <<= 1) {
        int y = __shfl_up(x, off, 64);
        if (lane >= off) x += y;
    }
    if (lane == 63) warp_sums[wid] = x;
    __syncthreads();
    int wbase = 0;
    for (int w = 0; w < wid; ++w) wbase += warp_sums[w];
    int run = wbase + x - tot;
    #pragma unroll
    for (int j = 0; j < 4; ++j) {
        int i = base + j;
        if (i < m) offs[i] = run;
        run += v4[j];
    }
    if (t == 255) bsum[blockIdx.x] = run;
}

// ---- scan phase 2: also writes the grand total into nodeoff[N].x ----
__global__ void scan2_kernel(int* __restrict__ bsum, int* __restrict__ offs,
                             int* __restrict__ noff, int nb, int m) {
    int lane = threadIdx.x;
    int run = 0;
    for (int base = 0; base < nb; base += 64) {
        int i = base + lane;
        int v = (i < nb) ? bsum[i] : 0;
        int x = v;
        #pragma unroll
        for (int off = 1; off < 64; off <<= 1) {
            int y = __shfl_up(x, off, 64);
            if (lane >= off) x += y;
        }
        if (i < nb) bsum[i] = run + x - v;
        run += __shfl(x, 63, 64);
    }
    if (lane == 0) {
        offs[m] = run;
        noff[(size_t)(m >> NSLICE_LOG) * 2] = run;       // nodeoff[N].x
        noff[(size_t)(m >> NSLICE_LOG) * 2 + 1] = run;   // nodeoff[N].y (unused)
    }
}

// ---- scan phase 3: add block prefix; emit compact per-node {e0, eb} ----
__global__ void scan3_kernel(int* __restrict__ offs, const int* __restrict__ bsum,
                             int* __restrict__ noff, int m) {
    int base = blockIdx.x * 1024 + threadIdx.x * 4;
    int add = bsum[blockIdx.x];
    #pragma unroll
    for (int j = 0; j < 4; ++j) {
        int i = base + j;
        if (i < m) {
            int o = offs[i] + add;
            offs[i] = o;
            int q = i & (NSLICE - 1);
            if (q == 0)  noff[(size_t)(i >> NSLICE_LOG) * 2] = o;       // e0
            if (q == 16) noff[(size_t)(i >> NSLICE_LOG) * 2 + 1] = o;   // eb
        }
    }
}

// ---- CSR fill: LDS cursors, zero global atomics, 2B entries (src as u16) ----
__global__ void fill_kernel(const int* __restrict__ s1, const int* __restrict__ d1,
                            const int* __restrict__ s2, const int* __restrict__ d2,
                            const int* __restrict__ offs, ushort_t* __restrict__ csr,
                            int N, int ne) {
    extern __shared__ int cur[];
    int t = threadIdx.x;
    int lo = blockIdx.x * CHUNKF;
    int q = blockIdx.y;
    int lim = N - lo < CHUNKF ? N - lo : CHUNKF;
    for (int j = t; j < lim; j += 1024)
        cur[j] = offs[(size_t)(lo + j) * NSLICE + q];
    __syncthreads();

    int SL = (2 * ne) / NSLICE;
    int g = q >= (NSLICE / 2);
    const int* src = g ? s2 : s1;
    const int* dst = g ? d2 : d1;
    int base = g ? ne : 0;
    int e0 = q * SL - base;
    int sl4 = SL & ~4095;
    int e1 = e0 + SL;

    for (int i = e0 + t * 4; i < e0 + sl4; i += 4096) {
        int4 d4 = *(const int4*)(dst + i);
        #pragma unroll
        for (int j = 0; j < 4; ++j) {
            int dd = ((const int*)&d4)[j] - lo;
            if ((unsigned)dd < (unsigned)lim) {
                int pos = atomicAdd(&cur[dd], 1);
                csr[pos] = (ushort_t)src[i + j];
            }
        }
    }
    for (int i = e0 + sl4 + t; i < e1; i += 1024) {
        int dd = dst[i] - lo;
        if ((unsigned)dd < (unsigned)lim) {
            int pos = atomicAdd(&cur[dd], 1);
            csr[pos] = (ushort_t)src[i];
        }
    }
}

// ---- W convert+transpose, both weights in one launch ----
__global__ void wconv2_kernel(const float* __restrict__ W1, const float* __restrict__ W2,
                              ushort_t* __restrict__ Wt1, ushort_t* __restrict__ Wt2) {
    int tid = blockIdx.x * 256 + threadIdx.x;
    if (tid < 128 * 128) {
        int ncol = tid / 128, k = tid % 128;
        Wt1[tid] = f2b(W1[(size_t)k * 128 + ncol]);
    } else if (tid < 128 * 128 + 64 * 128) {
        int t2 = tid - 128 * 128;
        int ncol = t2 / 128, k = t2 % 128;
        Wt2[t2] = f2b(W2[(size_t)k * 64 + ncol]);
    }
}

// ---- MFMA GEMM: Y[n,NOUT](bf16) = X[n,128] @ W ----
template<int NOUT, bool F32IN>
__global__ __launch_bounds__(256) void mfma_gemm_kernel(const void* __restrict__ Xv,
                                                        const ushort_t* __restrict__ Wt,
                                                        ushort_t* __restrict__ Y, int n) {
    constexpr int CT = NOUT / 16;
    const int lane = threadIdx.x & 63;
    const int wv = threadIdx.x >> 6;
    const int row0 = blockIdx.x * 64 + wv * 16;
    const int arow = row0 + (lane & 15);
    const int arc = arow < n ? arow : (n - 1);

    f32x4 acc[CT];
    #pragma unroll
    for (int ct = 0; ct < CT; ++ct) acc[ct] = (f32x4)(0.f);

    #pragma unroll
    for (int kk = 0; kk < 4; ++kk) {
        const int k0 = kk * 32 + (lane >> 4) * 8;
        bf16x8 a;
        if (F32IN) {
            const float* xp = (const float*)Xv + (size_t)arc * 128 + k0;
            float4 u0 = *(const float4*)xp;
            float4 u1 = *(const float4*)(xp + 4);
            a[0] = (short)f2b(u0.x); a[1] = (short)f2b(u0.y);
            a[2] = (short)f2b(u0.z); a[3] = (short)f2b(u0.w);
            a[4] = (short)f2b(u1.x); a[5] = (short)f2b(u1.y);
            a[6] = (short)f2b(u1.z); a[7] = (short)f2b(u1.w);
        } else {
            a = *(const bf16x8*)((const ushort_t*)Xv + (size_t)arc * 128 + k0);
        }
        #pragma unroll
        for (int ct = 0; ct < CT; ++ct) {
            bf16x8 b = *(const bf16x8*)(Wt + (size_t)(ct * 16 + (lane & 15)) * 128 + k0);
            acc[ct] = __builtin_amdgcn_mfma_f32_16x16x32_bf16(a, b, acc[ct], 0, 0, 0);
        }
    }

    const int orow0 = row0 + (lane >> 4) * 4;
    const int col = lane & 15;
    #pragma unroll
    for (int ct = 0; ct < CT; ++ct) {
        #pragma unroll
        for (int r = 0; r < 4; ++r) {
            int row = orow0 + r;
            if (row < n) Y[(size_t)row * NOUT + ct * 16 + col] = f2b(acc[ct][r]);
        }
    }
}

// ==== agg D=128: HALF-WAVE per edge (32 lanes x uint2 = 256B row) ====
__device__ __forceinline__ void consume128(const ushort_t* __restrict__ csr,
                                           const float* __restrict__ rso,
                                           const ushort_t* __restrict__ V,
                                           int hl, int half, int a, int b,
                                           float& acc0, float& acc1, float& acc2, float& acc3) {
    int e = a;
    for (; e + 16 <= b; e += 16) {
        int sv[8]; float wv[8]; uint2 uv[8];
        #pragma unroll
        for (int j = 0; j < 8; ++j) sv[j] = csr[e + 2 * j + half];
        #pragma unroll
        for (int j = 0; j < 8; ++j) wv[j] = rso[sv[j]];
        #pragma unroll
        for (int j = 0; j < 8; ++j)
            uv[j] = ((const uint2*)(V + (size_t)sv[j] * 128))[hl];
        #pragma unroll
        for (int j = 0; j < 8; ++j) {
            acc0 += wv[j] * b2f_lo(uv[j].x); acc1 += wv[j] * b2f_hi(uv[j].x);
            acc2 += wv[j] * b2f_lo(uv[j].y); acc3 += wv[j] * b2f_hi(uv[j].y);
        }
    }
    if (e < b) {   // masked batch over remaining 1..15 edges
        int sv[8]; float wv[8]; uint2 uv[8];
        #pragma unroll
        for (int j = 0; j < 8; ++j) {
            int idx = e + 2 * j + half;
            sv[j] = csr[idx < b ? idx : e];
        }
        #pragma unroll
        for (int j = 0; j < 8; ++j) {
            int idx = e + 2 * j + half;
            wv[j] = (idx < b) ? rso[sv[j]] : 0.f;
        }
        #pragma unroll
        for (int j = 0; j < 8; ++j)
            uv[j] = ((const uint2*)(V + (size_t)sv[j] * 128))[hl];
        #pragma unroll
        for (int j = 0; j < 8; ++j) {
            acc0 += wv[j] * b2f_lo(uv[j].x); acc1 += wv[j] * b2f_hi(uv[j].x);
            acc2 += wv[j] * b2f_lo(uv[j].y); acc3 += wv[j] * b2f_hi(uv[j].y);
        }
    }
}

__global__ void agg128_kernel(const ushort_t* __restrict__ V, const int2* __restrict__ noff,
                              const ushort_t* __restrict__ csr, const float* __restrict__ rs,
                              const float* __restrict__ bias, const float* __restrict__ attn,
                              uint_t* __restrict__ out, int n) {
    int wid = (int)(((size_t)blockIdx.x * blockDim.x + threadIdx.x) >> 6);
    int lane = threadIdx.x & 63;
    int half = lane >> 5;
    int hl = lane & 31;
    if (wid >= n) return;
    int2 nv = noff[wid];
    int e0 = nv.x, eb = nv.y;
    int e1 = noff[wid + 1].x;

    float s10 = 0.f, s11 = 0.f, s12 = 0.f, s13 = 0.f;
    float s20 = 0.f, s21 = 0.f, s22 = 0.f, s23 = 0.f;
    consume128(csr, rs, V, hl, half, e0, eb, s10, s11, s12, s13);                 // graph 1
    consume128(csr, rs + 2 * (size_t)n, V, hl, half, eb, e1, s20, s21, s22, s23); // graph 2

    float f1 = attn[0] * rs[(size_t)n + wid];
    float f2 = attn[1] * rs[3 * (size_t)n + wid];
    float c0 = f1 * s10 + f2 * s20;
    float c1 = f1 * s11 + f2 * s21;
    float c2 = f1 * s12 + f2 * s22;
    float c3 = f1 * s13 + f2 * s23;
    c0 += __shfl_xor(c0, 32, 64);
    c1 += __shfl_xor(c1, 32, 64);
    c2 += __shfl_xor(c2, 32, 64);
    c3 += __shfl_xor(c3, 32, 64);

    if (half == 0) {
        float bs = attn[0] + attn[1];
        float4 bb = ((const float4*)bias)[hl];
        uint2 o;
        o.x = (uint_t)f2b(c0 + bs * bb.x) | ((uint_t)f2b(c1 + bs * bb.y) << 16);
        o.y = (uint_t)f2b(c2 + bs * bb.z) | ((uint_t)f2b(c3 + bs * bb.w) << 16);
        ((uint2*)(out + (size_t)wid * 64))[hl] = o;
    }
}

// ==== agg D=64: QUARTER-WAVE per edge (16 lanes x uint2 = 128B row) ====
__device__ __forceinline__ void consume64(const ushort_t* __restrict__ csr,
                                          const float* __restrict__ rso,
                                          const ushort_t* __restrict__ V,
                                          int ql, int quarter, int a, int b,
                                          float& acc0, float& acc1, float& acc2, float& acc3) {
    int e = a;
    for (; e + 32 <= b; e += 32) {
        int sv[8]; float wv[8]; uint2 uv[8];
        #pragma unroll
        for (int j = 0; j < 8; ++j) sv[j] = csr[e + 4 * j + quarter];
        #pragma unroll
        for (int j = 0; j < 8; ++j) wv[j] = rso[sv[j]];
        #pragma unroll
        for (int j = 0; j < 8; ++j)
            uv[j] = ((const uint2*)(V + (size_t)sv[j] * 64))[ql];
        #pragma unroll
        for (int j = 0; j < 8; ++j) {
            acc0 += wv[j] * b2f_lo(uv[j].x); acc1 += wv[j] * b2f_hi(uv[j].x);
            acc2 += wv[j] * b2f_lo(uv[j].y); acc3 += wv[j] * b2f_hi(uv[j].y);
        }
    }
    if (e < b) {   // masked batch over remaining 1..31 edges
        int sv[8]; float wv[8]; uint2 uv[8];
        #pragma unroll
        for (int j = 0; j < 8; ++j) {
            int idx = e + 4 * j + quarter;
            sv[j] = csr[idx < b ? idx : e];
        }
        #pragma unroll
        for (int j = 0; j < 8; ++j) {
            int idx = e + 4 * j + quarter;
            wv[j] = (idx < b) ? rso[sv[j]] : 0.f;
        }
        #pragma unroll
        for (int j = 0; j < 8; ++j)
            uv[j] = ((const uint2*)(V + (size_t)sv[j] * 64))[ql];
        #pragma unroll
        for (int j = 0; j < 8; ++j) {
            acc0 += wv[j] * b2f_lo(uv[j].x); acc1 += wv[j] * b2f_hi(uv[j].x);
            acc2 += wv[j] * b2f_lo(uv[j].y); acc3 += wv[j] * b2f_hi(uv[j].y);
        }
    }
}

__global__ void agg64_kernel(const ushort_t* __restrict__ V, const int2* __restrict__ noff,
                             const ushort_t* __restrict__ csr, const float* __restrict__ rs,
                             const float* __restrict__ bias, const float* __restrict__ attn,
                             float* __restrict__ out, int n) {
    int wid = (int)(((size_t)blockIdx.x * blockDim.x + threadIdx.x) >> 6);
    int lane = threadIdx.x & 63;
    int quarter = lane >> 4;
    int ql = lane & 15;
    if (wid >= n) return;
    int2 nv = noff[wid];
    int e0 = nv.x, eb = nv.y;
    int e1 = noff[wid + 1].x;

    float s10 = 0.f, s11 = 0.f, s12 = 0.f, s13 = 0.f;
    float s20 = 0.f, s21 = 0.f, s22 = 0.f, s23 = 0.f;
    consume64(csr, rs, V, ql, quarter, e0, eb, s10, s11, s12, s13);                 // graph 1
    consume64(csr, rs + 2 * (size_t)n, V, ql, quarter, eb, e1, s20, s21, s22, s23); // graph 2

    float f1 = attn[0] * rs[(size_t)n + wid];
    float f2 = attn[1] * rs[3 * (size_t)n + wid];
    float c0 = f1 * s10 + f2 * s20;
    float c1 = f1 * s11 + f2 * s21;
    float c2 = f1 * s12 + f2 * s22;
    float c3 = f1 * s13 + f2 * s23;
    c0 += __shfl_xor(c0, 16, 64); c0 += __shfl_xor(c0, 32, 64);
    c1 += __shfl_xor(c1, 16, 64); c1 += __shfl_xor(c1, 32, 64);
    c2 += __shfl_xor(c2, 16, 64); c2 += __shfl_xor(c2, 32, 64);
    c3 += __shfl_xor(c3, 16, 64); c3 += __shfl_xor(c3, 32, 64);

    if (quarter == 0) {
        float bs = attn[0] + attn[1];
        float4 bb = ((const float4*)bias)[ql];
        float4 o = make_float4(c0 + bs * bb.x, c1 + bs * bb.y,
                               c2 + bs * bb.z, c3 + bs * bb.w);
        ((float4*)(out + (size_t)wid * 64))[ql] = o;
    }
}

extern "C" void kernel_launch(void* const* d_in, const int* in_sizes, int n_in,
                              void* d_out, int out_size, void* d_ws, size_t ws_size,
                              hipStream_t stream) {
    const float* feat = (const float*)d_in[0];
    const int* src1   = (const int*)d_in[1];
    const int* dst1   = (const int*)d_in[2];
    const int* src2   = (const int*)d_in[3];
    const int* dst2   = (const int*)d_in[4];
    const float* attn = (const float*)d_in[5];
    const float* W1   = (const float*)d_in[6];
    const float* b1   = (const float*)d_in[7];
    const float* W2   = (const float*)d_in[8];
    const float* b2   = (const float*)d_in[9];
    float* out = (float*)d_out;

    const int N  = in_sizes[0] / DINF;        // 50000
    const int NE = in_sizes[1];               // 600000
    const int M  = NSLICE * N;                // offs length (1.6M), node-major
    const int NB2 = (M + 1023) / 1024;        // scan blocks

    // workspace layout:
    // Wt1 | Wt2 | A bf16[N*128] | B bf16[N*128] | C bf16[N*64] |
    // offs[M+1] | noff int2[N+1] | cntS[M] | cntD[M] | rs f32[4N] | bsum[NB2]
    // csr (u16[2NE] = 2.4 MB) OVERLAYS cntS (6.4 MB): counts dead after scan1.
    ushort_t* Wt1 = (ushort_t*)d_ws;
    ushort_t* Wt2 = Wt1 + 128 * 128;
    ushort_t* A   = Wt2 + 64 * 128;
    ushort_t* B   = A + (size_t)N * DHID;
    ushort_t* C   = B + (size_t)N * DHID;
    int* offs   = (int*)(C + (size_t)N * DOUTF);
    int* noff   = offs + (M + 1);             // int2[N+1] as int pairs
    int* cntS   = noff + 2 * (N + 1);
    int* cntD   = cntS + M;
    float* rs   = (float*)(cntD + M);
    int* bsum   = (int*)(rs + 4 * (size_t)N);
    ushort_t* csr = (ushort_t*)cntS;          // overlay

    wconv2_kernel<<<(128 * 128 + 64 * 128 + 255) / 256, 256, 0, stream>>>(W1, W2, Wt1, Wt2);

    cnt_kernel<<<dim3(NCHUNKC, NSLICE, 2), 1024, CHUNKC * sizeof(int), stream>>>(
        src1, dst1, src2, dst2, cntS, cntD, N, NE);

    degred_kernel<<<(N + 255) / 256, 256, 0, stream>>>(cntS, cntD, rs, N);

    scan1_kernel<<<NB2, 256, 0, stream>>>(cntD, offs, bsum, N, M);
    scan2_kernel<<<1, 64, 0, stream>>>(bsum, offs, noff, NB2, M);
    scan3_kernel<<<NB2, 256, 0, stream>>>(offs, bsum, noff, M);

    fill_kernel<<<dim3(NCHUNKF, NSLICE), 1024, CHUNKF * sizeof(int), stream>>>(
        src1, dst1, src2, dst2, offs, csr, N, NE);

    int gb = (N + 63) / 64;
    int ab = (N + 3) / 4;
    // layer 1: A = bf16(feat @ W1) ; B = bf16(agg(A))
    mfma_gemm_kernel<DHID, true><<<gb, 256, 0, stream>>>(feat, Wt1, A, N);
    agg128_kernel<<<ab, 256, 0, stream>>>(A, (const int2*)noff, csr, rs, b1, attn, (uint_t*)B, N);

    // layer 2: C = bf16(B @ W2) ; out = agg(C)  (f32)
    mfma_gemm_kernel<DOUTF, false><<<gb, 256, 0, stream>>>(B, Wt2, C, N);
    agg64_kernel<<<ab, 256, 0, stream>>>(C, (const int2*)noff, csr, rs, b2, attn, out, N);
}

// Round 17
// 191.229 us; speedup vs baseline: 1.1752x; 1.0231x over previous
//
#include <hip/hip_runtime.h>

#define DINF 128
#define DHID 128
#define DOUTF 64

#define NSLICE 32       // edge slices (16 per graph); CSR node-major, slice-minor
#define NSLICE_LOG 5
#define CHUNKC 12544    // cnt histogram chunk (49 KB LDS)
#define NCHUNKC 4
#define CHUNKF 6272     // fill cursor chunk (24.5 KB LDS)
#define NCHUNKF 8

typedef unsigned short ushort_t;
typedef unsigned int uint_t;
typedef __attribute__((ext_vector_type(8))) short bf16x8;
typedef __attribute__((ext_vector_type(4))) float f32x4;

__device__ __forceinline__ ushort_t f2b(float x) {   // f32 -> bf16 RNE
    uint_t u = __float_as_uint(x);
    u += 0x7fffu + ((u >> 16) & 1u);
    return (ushort_t)(u >> 16);
}
__device__ __forceinline__ float b2f_lo(uint_t u) { return __uint_as_float(u << 16); }
__device__ __forceinline__ float b2f_hi(uint_t u) { return __uint_as_float(u & 0xffff0000u); }

// ---- per-(slice, node) histograms of src and dst; plain stores, int4 stream ----
__global__ void cnt_kernel(const int* __restrict__ s1, const int* __restrict__ d1,
                           const int* __restrict__ s2, const int* __restrict__ d2,
                           int* __restrict__ cntS, int* __restrict__ cntD, int N, int ne) {
    extern __shared__ int h[];
    int t = threadIdx.x;
    for (int j = t; j < CHUNKC; j += 1024) h[j] = 0;
    __syncthreads();

    int lo = blockIdx.x * CHUNKC;
    int q = blockIdx.y;
    bool isSrc = blockIdx.z == 0;
    int SL = (2 * ne) / NSLICE;           // 37500, %4==0, slice starts 16B-aligned
    int g = q >= (NSLICE / 2);
    const int* p = g ? (isSrc ? s2 : d2) : (isSrc ? s1 : d1);
    int base = g ? ne : 0;
    int e0 = q * SL - base;
    int e1 = e0 + SL;
    for (int i = e0 + t * 4; i + 3 < e1; i += 4096) {
        int4 v4 = *(const int4*)(p + i);
        #pragma unroll
        for (int j = 0; j < 4; ++j) {
            int v = ((const int*)&v4)[j] - lo;
            if ((unsigned)v < (unsigned)CHUNKC) atomicAdd(&h[v], 1);
        }
    }
    __syncthreads();

    int* c = (isSrc ? cntS : cntD) + (size_t)q * N;
    for (int j = t; j < CHUNKC; j += 1024) {
        int node = lo + j;
        if (node < N) c[node] = h[j];
    }
}

// ---- degrees -> rsqrt table; ALSO transpose cntD into node-major cntT ----
__global__ void degred_kernel(const int* __restrict__ cntS, const int* __restrict__ cntD,
                              float* __restrict__ rs, int* __restrict__ cntT, int N) {
    int v = blockIdx.x * 256 + threadIdx.x;
    if (v >= N) return;
    int cs[NSLICE], cd[NSLICE];
    #pragma unroll
    for (int q = 0; q < NSLICE; ++q) {
        cs[q] = cntS[(size_t)q * N + v];
        cd[q] = cntD[(size_t)q * N + v];
    }
    int o1 = 0, i1 = 0, o2 = 0, i2 = 0;
    #pragma unroll
    for (int q = 0; q < NSLICE / 2; ++q) { o1 += cs[q]; i1 += cd[q]; }
    #pragma unroll
    for (int q = NSLICE / 2; q < NSLICE; ++q) { o2 += cs[q]; i2 += cd[q]; }
    rs[v]                  = rsqrtf(fmaxf((float)o1, 1.0f));   // rs1o
    rs[N + v]              = rsqrtf(fmaxf((float)i1, 1.0f));   // rs1i
    rs[2 * (size_t)N + v]  = rsqrtf(fmaxf((float)o2, 1.0f));   // rs2o
    rs[3 * (size_t)N + v]  = rsqrtf(fmaxf((float)i2, 1.0f));   // rs2i
    #pragma unroll
    for (int q = 0; q < NSLICE; q += 4)
        *(int4*)(cntT + (size_t)v * NSLICE + q) =
            make_int4(cd[q], cd[q + 1], cd[q + 2], cd[q + 3]);
}

// ---- scan phase 1: node-major, COALESCED read of cntT ----
__global__ void scan1_kernel(const int* __restrict__ cntT, int* __restrict__ offs,
                             int* __restrict__ bsum, int m) {
    __shared__ int warp_sums[4];
    int t = threadIdx.x;
    int lane = t & 63;
    int wid = t >> 6;
    int base = blockIdx.x * 1024 + t * 4;

    int v4[4];
    int tot = 0;
    #pragma unroll
    for (int j = 0; j < 4; ++j) {
        int i = base + j;
        int d = (i < m) ? cntT[i] : 0;
        v4[j] = d; tot += d;
    }
    int x = tot;
    #pragma unroll
    for (int off = 1; off < 64; off <<= 1) {
        int y = __shfl_up(x, off, 64);
        if (lane >= off) x += y;
    }
    if (lane == 63) warp_sums[wid] = x;
    __syncthreads();
    int wbase = 0;
    for (int w = 0; w < wid; ++w) wbase += warp_sums[w];
    int run = wbase + x - tot;
    #pragma unroll
    for (int j = 0; j < 4; ++j) {
        int i = base + j;
        if (i < m) offs[i] = run;
        run += v4[j];
    }
    if (t == 255) bsum[blockIdx.x] = run;
}

// ---- scan phase 2: block sums; grand total into noff[N].x ----
__global__ void scan2_kernel(int* __restrict__ bsum, int* __restrict__ offs,
                             int* __restrict__ noff, int nb, int m) {
    int lane = threadIdx.x;
    int run = 0;
    for (int base = 0; base < nb; base += 64) {
        int i = base + lane;
        int v = (i < nb) ? bsum[i] : 0;
        int x = v;
        #pragma unroll
        for (int off = 1; off < 64; off <<= 1) {
            int y = __shfl_up(x, off, 64);
            if (lane >= off) x += y;
        }
        if (i < nb) bsum[i] = run + x - v;
        run += __shfl(x, 63, 64);
    }
    if (lane == 0) {
        offs[m] = run;
        noff[(size_t)(m >> NSLICE_LOG) * 2] = run;       // nodeoff[N].x
        noff[(size_t)(m >> NSLICE_LOG) * 2 + 1] = run;   // nodeoff[N].y (unused)
    }
}

// ---- scan phase 3: add block prefix; emit SLICE-MAJOR offs_sm + compact noff ----
__global__ void scan3_kernel(const int* __restrict__ offs, const int* __restrict__ bsum,
                             int* __restrict__ offs_sm, int* __restrict__ noff,
                             int N, int m) {
    int base = blockIdx.x * 1024 + threadIdx.x * 4;
    int add = bsum[blockIdx.x];
    #pragma unroll
    for (int j = 0; j < 4; ++j) {
        int i = base + j;
        if (i < m) {
            int o = offs[i] + add;
            int v = i >> NSLICE_LOG;
            int q = i & (NSLICE - 1);
            offs_sm[(size_t)q * N + v] = o;
            if (q == 0)  noff[(size_t)v * 2] = o;       // e0
            if (q == 16) noff[(size_t)v * 2 + 1] = o;   // eb
        }
    }
}

// ---- CSR fill: LDS cursors (init from slice-major offs, coalesced), u16 entries ----
__global__ void fill_kernel(const int* __restrict__ s1, const int* __restrict__ d1,
                            const int* __restrict__ s2, const int* __restrict__ d2,
                            const int* __restrict__ offs_sm, ushort_t* __restrict__ csr,
                            int N, int ne) {
    extern __shared__ int cur[];
    int t = threadIdx.x;
    int lo = blockIdx.x * CHUNKF;
    int q = blockIdx.y;
    int lim = N - lo < CHUNKF ? N - lo : CHUNKF;
    const int* ob = offs_sm + (size_t)q * N + lo;
    for (int j = t; j < lim; j += 1024)
        cur[j] = ob[j];
    __syncthreads();

    int SL = (2 * ne) / NSLICE;
    int g = q >= (NSLICE / 2);
    const int* src = g ? s2 : s1;
    const int* dst = g ? d2 : d1;
    int base = g ? ne : 0;
    int e0 = q * SL - base;
    int sl4 = SL & ~4095;
    int e1 = e0 + SL;

    for (int i = e0 + t * 4; i < e0 + sl4; i += 4096) {
        int4 d4 = *(const int4*)(dst + i);
        #pragma unroll
        for (int j = 0; j < 4; ++j) {
            int dd = ((const int*)&d4)[j] - lo;
            if ((unsigned)dd < (unsigned)lim) {
                int pos = atomicAdd(&cur[dd], 1);
                csr[pos] = (ushort_t)src[i + j];
            }
        }
    }
    for (int i = e0 + sl4 + t; i < e1; i += 1024) {
        int dd = dst[i] - lo;
        if ((unsigned)dd < (unsigned)lim) {
            int pos = atomicAdd(&cur[dd], 1);
            csr[pos] = (ushort_t)src[i];
        }
    }
}

// ---- W convert+transpose, both weights in one launch ----
__global__ void wconv2_kernel(const float* __restrict__ W1, const float* __restrict__ W2,
                              ushort_t* __restrict__ Wt1, ushort_t* __restrict__ Wt2) {
    int tid = blockIdx.x * 256 + threadIdx.x;
    if (tid < 128 * 128) {
        int ncol = tid / 128, k = tid % 128;
        Wt1[tid] = f2b(W1[(size_t)k * 128 + ncol]);
    } else if (tid < 128 * 128 + 64 * 128) {
        int t2 = tid - 128 * 128;
        int ncol = t2 / 128, k = t2 % 128;
        Wt2[t2] = f2b(W2[(size_t)k * 64 + ncol]);
    }
}

// ---- MFMA GEMM: Y[n,NOUT](bf16) = X[n,128] @ W ----
template<int NOUT, bool F32IN>
__global__ __launch_bounds__(256) void mfma_gemm_kernel(const void* __restrict__ Xv,
                                                        const ushort_t* __restrict__ Wt,
                                                        ushort_t* __restrict__ Y, int n) {
    constexpr int CT = NOUT / 16;
    const int lane = threadIdx.x & 63;
    const int wv = threadIdx.x >> 6;
    const int row0 = blockIdx.x * 64 + wv * 16;
    const int arow = row0 + (lane & 15);
    const int arc = arow < n ? arow : (n - 1);

    f32x4 acc[CT];
    #pragma unroll
    for (int ct = 0; ct < CT; ++ct) acc[ct] = (f32x4)(0.f);

    #pragma unroll
    for (int kk = 0; kk < 4; ++kk) {
        const int k0 = kk * 32 + (lane >> 4) * 8;
        bf16x8 a;
        if (F32IN) {
            const float* xp = (const float*)Xv + (size_t)arc * 128 + k0;
            float4 u0 = *(const float4*)xp;
            float4 u1 = *(const float4*)(xp + 4);
            a[0] = (short)f2b(u0.x); a[1] = (short)f2b(u0.y);
            a[2] = (short)f2b(u0.z); a[3] = (short)f2b(u0.w);
            a[4] = (short)f2b(u1.x); a[5] = (short)f2b(u1.y);
            a[6] = (short)f2b(u1.z); a[7] = (short)f2b(u1.w);
        } else {
            a = *(const bf16x8*)((const ushort_t*)Xv + (size_t)arc * 128 + k0);
        }
        #pragma unroll
        for (int ct = 0; ct < CT; ++ct) {
            bf16x8 b = *(const bf16x8*)(Wt + (size_t)(ct * 16 + (lane & 15)) * 128 + k0);
            acc[ct] = __builtin_amdgcn_mfma_f32_16x16x32_bf16(a, b, acc[ct], 0, 0, 0);
        }
    }

    const int orow0 = row0 + (lane >> 4) * 4;
    const int col = lane & 15;
    #pragma unroll
    for (int ct = 0; ct < CT; ++ct) {
        #pragma unroll
        for (int r = 0; r < 4; ++r) {
            int row = orow0 + r;
            if (row < n) Y[(size_t)row * NOUT + ct * 16 + col] = f2b(acc[ct][r]);
        }
    }
}

// ==== agg D=128: HALF-WAVE per edge (32 lanes x uint2 = 256B row) ====
__device__ __forceinline__ void consume128(const ushort_t* __restrict__ csr,
                                           const float* __restrict__ rso,
                                           const ushort_t* __restrict__ V,
                                           int hl, int half, int a, int b,
                                           float& acc0, float& acc1, float& acc2, float& acc3) {
    int e = a;
    for (; e + 16 <= b; e += 16) {
        int sv[8]; float wv[8]; uint2 uv[8];
        #pragma unroll
        for (int j = 0; j < 8; ++j) sv[j] = csr[e + 2 * j + half];
        #pragma unroll
        for (int j = 0; j < 8; ++j) wv[j] = rso[sv[j]];
        #pragma unroll
        for (int j = 0; j < 8; ++j)
            uv[j] = ((const uint2*)(V + (size_t)sv[j] * 128))[hl];
        #pragma unroll
        for (int j = 0; j < 8; ++j) {
            acc0 += wv[j] * b2f_lo(uv[j].x); acc1 += wv[j] * b2f_hi(uv[j].x);
            acc2 += wv[j] * b2f_lo(uv[j].y); acc3 += wv[j] * b2f_hi(uv[j].y);
        }
    }
    if (e < b) {   // masked batch over remaining 1..15 edges
        int sv[8]; float wv[8]; uint2 uv[8];
        #pragma unroll
        for (int j = 0; j < 8; ++j) {
            int idx = e + 2 * j + half;
            sv[j] = csr[idx < b ? idx : e];
        }
        #pragma unroll
        for (int j = 0; j < 8; ++j) {
            int idx = e + 2 * j + half;
            wv[j] = (idx < b) ? rso[sv[j]] : 0.f;
        }
        #pragma unroll
        for (int j = 0; j < 8; ++j)
            uv[j] = ((const uint2*)(V + (size_t)sv[j] * 128))[hl];
        #pragma unroll
        for (int j = 0; j < 8; ++j) {
            acc0 += wv[j] * b2f_lo(uv[j].x); acc1 += wv[j] * b2f_hi(uv[j].x);
            acc2 += wv[j] * b2f_lo(uv[j].y); acc3 += wv[j] * b2f_hi(uv[j].y);
        }
    }
}

__global__ void agg128_kernel(const ushort_t* __restrict__ V, const int2* __restrict__ noff,
                              const ushort_t* __restrict__ csr, const float* __restrict__ rs,
                              const float* __restrict__ bias, const float* __restrict__ attn,
                              uint_t* __restrict__ out, int n) {
    int wid = (int)(((size_t)blockIdx.x * blockDim.x + threadIdx.x) >> 6);
    int lane = threadIdx.x & 63;
    int half = lane >> 5;
    int hl = lane & 31;
    if (wid >= n) return;
    int2 nv = noff[wid];
    int e0 = nv.x, eb = nv.y;
    int e1 = noff[wid + 1].x;

    float s10 = 0.f, s11 = 0.f, s12 = 0.f, s13 = 0.f;
    float s20 = 0.f, s21 = 0.f, s22 = 0.f, s23 = 0.f;
    consume128(csr, rs, V, hl, half, e0, eb, s10, s11, s12, s13);                 // graph 1
    consume128(csr, rs + 2 * (size_t)n, V, hl, half, eb, e1, s20, s21, s22, s23); // graph 2

    float f1 = attn[0] * rs[(size_t)n + wid];
    float f2 = attn[1] * rs[3 * (size_t)n + wid];
    float c0 = f1 * s10 + f2 * s20;
    float c1 = f1 * s11 + f2 * s21;
    float c2 = f1 * s12 + f2 * s22;
    float c3 = f1 * s13 + f2 * s23;
    c0 += __shfl_xor(c0, 32, 64);
    c1 += __shfl_xor(c1, 32, 64);
    c2 += __shfl_xor(c2, 32, 64);
    c3 += __shfl_xor(c3, 32, 64);

    if (half == 0) {
        float bs = attn[0] + attn[1];
        float4 bb = ((const float4*)bias)[hl];
        uint2 o;
        o.x = (uint_t)f2b(c0 + bs * bb.x) | ((uint_t)f2b(c1 + bs * bb.y) << 16);
        o.y = (uint_t)f2b(c2 + bs * bb.z) | ((uint_t)f2b(c3 + bs * bb.w) << 16);
        ((uint2*)(out + (size_t)wid * 64))[hl] = o;
    }
}

// ==== agg D=64: QUARTER-WAVE per edge (16 lanes x uint2 = 128B row) ====
__device__ __forceinline__ void consume64(const ushort_t* __restrict__ csr,
                                          const float* __restrict__ rso,
                                          const ushort_t* __restrict__ V,
                                          int ql, int quarter, int a, int b,
                                          float& acc0, float& acc1, float& acc2, float& acc3) {
    int e = a;
    for (; e + 32 <= b; e += 32) {
        int sv[8]; float wv[8]; uint2 uv[8];
        #pragma unroll
        for (int j = 0; j < 8; ++j) sv[j] = csr[e + 4 * j + quarter];
        #pragma unroll
        for (int j = 0; j < 8; ++j) wv[j] = rso[sv[j]];
        #pragma unroll
        for (int j = 0; j < 8; ++j)
            uv[j] = ((const uint2*)(V + (size_t)sv[j] * 64))[ql];
        #pragma unroll
        for (int j = 0; j < 8; ++j) {
            acc0 += wv[j] * b2f_lo(uv[j].x); acc1 += wv[j] * b2f_hi(uv[j].x);
            acc2 += wv[j] * b2f_lo(uv[j].y); acc3 += wv[j] * b2f_hi(uv[j].y);
        }
    }
    if (e < b) {   // masked batch over remaining 1..31 edges
        int sv[8]; float wv[8]; uint2 uv[8];
        #pragma unroll
        for (int j = 0; j < 8; ++j) {
            int idx = e + 4 * j + quarter;
            sv[j] = csr[idx < b ? idx : e];
        }
        #pragma unroll
        for (int j = 0; j < 8; ++j) {
            int idx = e + 4 * j + quarter;
            wv[j] = (idx < b) ? rso[sv[j]] : 0.f;
        }
        #pragma unroll
        for (int j = 0; j < 8; ++j)
            uv[j] = ((const uint2*)(V + (size_t)sv[j] * 64))[ql];
        #pragma unroll
        for (int j = 0; j < 8; ++j) {
            acc0 += wv[j] * b2f_lo(uv[j].x); acc1 += wv[j] * b2f_hi(uv[j].x);
            acc2 += wv[j] * b2f_lo(uv[j].y); acc3 += wv[j] * b2f_hi(uv[j].y);
        }
    }
}

__global__ void agg64_kernel(const ushort_t* __restrict__ V, const int2* __restrict__ noff,
                             const ushort_t* __restrict__ csr, const float* __restrict__ rs,
                             const float* __restrict__ bias, const float* __restrict__ attn,
                             float* __restrict__ out, int n) {
    int wid = (int)(((size_t)blockIdx.x * blockDim.x + threadIdx.x) >> 6);
    int lane = threadIdx.x & 63;
    int quarter = lane >> 4;
    int ql = lane & 15;
    if (wid >= n) return;
    int2 nv = noff[wid];
    int e0 = nv.x, eb = nv.y;
    int e1 = noff[wid + 1].x;

    float s10 = 0.f, s11 = 0.f, s12 = 0.f, s13 = 0.f;
    float s20 = 0.f, s21 = 0.f, s22 = 0.f, s23 = 0.f;
    consume64(csr, rs, V, ql, quarter, e0, eb, s10, s11, s12, s13);                 // graph 1
    consume64(csr, rs + 2 * (size_t)n, V, ql, quarter, eb, e1, s20, s21, s22, s23); // graph 2

    float f1 = attn[0] * rs[(size_t)n + wid];
    float f2 = attn[1] * rs[3 * (size_t)n + wid];
    float c0 = f1 * s10 + f2 * s20;
    float c1 = f1 * s11 + f2 * s21;
    float c2 = f1 * s12 + f2 * s22;
    float c3 = f1 * s13 + f2 * s23;
    c0 += __shfl_xor(c0, 16, 64); c0 += __shfl_xor(c0, 32, 64);
    c1 += __shfl_xor(c1, 16, 64); c1 += __shfl_xor(c1, 32, 64);
    c2 += __shfl_xor(c2, 16, 64); c2 += __shfl_xor(c2, 32, 64);
    c3 += __shfl_xor(c3, 16, 64); c3 += __shfl_xor(c3, 32, 64);

    if (quarter == 0) {
        float bs = attn[0] + attn[1];
        float4 bb = ((const float4*)bias)[ql];
        float4 o = make_float4(c0 + bs * bb.x, c1 + bs * bb.y,
                               c2 + bs * bb.z, c3 + bs * bb.w);
        ((float4*)(out + (size_t)wid * 64))[ql] = o;
    }
}

extern "C" void kernel_launch(void* const* d_in, const int* in_sizes, int n_in,
                              void* d_out, int out_size, void* d_ws, size_t ws_size,
                              hipStream_t stream) {
    const float* feat = (const float*)d_in[0];
    const int* src1   = (const int*)d_in[1];
    const int* dst1   = (const int*)d_in[2];
    const int* src2   = (const int*)d_in[3];
    const int* dst2   = (const int*)d_in[4];
    const float* attn = (const float*)d_in[5];
    const float* W1   = (const float*)d_in[6];
    const float* b1   = (const float*)d_in[7];
    const float* W2   = (const float*)d_in[8];
    const float* b2   = (const float*)d_in[9];
    float* out = (float*)d_out;

    const int N  = in_sizes[0] / DINF;        // 50000
    const int NE = in_sizes[1];               // 600000
    const int M  = NSLICE * N;                // 1.6M logical offsets, node-major
    const int NB2 = (M + 1023) / 1024;        // scan blocks

    // workspace layout:
    // Wt1 | Wt2 | A bf16[N*128] | B bf16[N*128] | C bf16[N*64] |
    // offs[M+1] | noff int2[N+1] | cntS[M] | cntD[M] | cntT[M] | rs f32[4N] | bsum
    // csr (u16[2NE]=2.4MB) OVERLAYS cntS; offs_sm[M] OVERLAYS cntD
    // (both dead after degred/scan1).
    ushort_t* Wt1 = (ushort_t*)d_ws;
    ushort_t* Wt2 = Wt1 + 128 * 128;
    ushort_t* A   = Wt2 + 64 * 128;
    ushort_t* B   = A + (size_t)N * DHID;
    ushort_t* C   = B + (size_t)N * DHID;
    int* offs   = (int*)(C + (size_t)N * DOUTF);
    int* noff   = offs + (M + 1);             // int2[N+1] as int pairs
    int* cntS   = noff + 2 * (N + 1);
    int* cntD   = cntS + M;
    int* cntT   = cntD + M;
    float* rs   = (float*)(cntT + M);
    int* bsum   = (int*)(rs + 4 * (size_t)N);
    ushort_t* csr = (ushort_t*)cntS;          // overlay (cntS dead after degred)
    int* offs_sm  = cntD;                     // overlay (cntD dead after degred)

    wconv2_kernel<<<(128 * 128 + 64 * 128 + 255) / 256, 256, 0, stream>>>(W1, W2, Wt1, Wt2);

    cnt_kernel<<<dim3(NCHUNKC, NSLICE, 2), 1024, CHUNKC * sizeof(int), stream>>>(
        src1, dst1, src2, dst2, cntS, cntD, N, NE);

    degred_kernel<<<(N + 255) / 256, 256, 0, stream>>>(cntS, cntD, rs, cntT, N);

    scan1_kernel<<<NB2, 256, 0, stream>>>(cntT, offs, bsum, M);
    scan2_kernel<<<1, 64, 0, stream>>>(bsum, offs, noff, NB2, M);
    scan3_kernel<<<NB2, 256, 0, stream>>>(offs, bsum, offs_sm, noff, N, M);

    fill_kernel<<<dim3(NCHUNKF, NSLICE), 1024, CHUNKF * sizeof(int), stream>>>(
        src1, dst1, src2, dst2, offs_sm, csr, N, NE);

    int gb = (N + 63) / 64;
    int ab = (N + 3) / 4;
    // layer 1: A = bf16(feat @ W1) ; B = bf16(agg(A))
    mfma_gemm_kernel<DHID, true><<<gb, 256, 0, stream>>>(feat, Wt1, A, N);
    agg128_kernel<<<ab, 256, 0, stream>>>(A, (const int2*)noff, csr, rs, b1, attn, (uint_t*)B, N);

    // layer 2: C = bf16(B @ W2) ; out = agg(C)  (f32)
    mfma_gemm_kernel<DOUTF, false><<<gb, 256, 0, stream>>>(B, Wt2, C, N);
    agg64_kernel<<<ab, 256, 0, stream>>>(C, (const int2*)noff, csr, rs, b2, attn, out, N);
}